// Round 2
// baseline (230.936 us; speedup 1.0000x reference)
//
#include <hip/hip_runtime.h>

typedef unsigned short ushort_t;
typedef __attribute__((ext_vector_type(8))) __bf16 bf16x8;
typedef __attribute__((ext_vector_type(4))) float floatx4;

__device__ __forceinline__ ushort_t f2bf(float f) {
    unsigned int u = __builtin_bit_cast(unsigned int, f);
    u = (u + 0x7fffu + ((u >> 16) & 1u)) >> 16;
    return (ushort_t)u;
}

__device__ __forceinline__ void async16(const ushort_t* g, ushort_t* l) {
    __builtin_amdgcn_global_load_lds(
        (const __attribute__((address_space(1))) unsigned int*)g,
        (__attribute__((address_space(3))) unsigned int*)l,
        16 /*bytes*/, 0 /*offset*/, 0 /*aux*/);
}

// XOR-swizzled LDS offset (ushort index) of the 8-elem group (row, cg).
// (legacy core)
__device__ __forceinline__ int sw(int row, int cg) {
    return ((row << 2) + ((cg ^ row ^ (row >> 2)) & 3)) << 3;
}

// XCD-chunked bijective blockIdx swizzle (nwg % 8 == 0).
__device__ __forceinline__ int xcd_swz(int bid, int cpx) {
    return (bid & 7) * cpx + (bid >> 3);
}

template <int N>
__device__ __forceinline__ void vwait() {
    if constexpr (N == 0)      asm volatile("s_waitcnt vmcnt(0)" ::: "memory");
    else if constexpr (N == 3) asm volatile("s_waitcnt vmcnt(3)" ::: "memory");
    else if constexpr (N == 4) asm volatile("s_waitcnt vmcnt(4)" ::: "memory");
    else if constexpr (N == 6) asm volatile("s_waitcnt vmcnt(6)" ::: "memory");
    else if constexpr (N == 8) asm volatile("s_waitcnt vmcnt(8)" ::: "memory");
    else static_assert(N == 0, "unsupported vmcnt");
}

// ---------------------------------------------------------------------------
// Legacy NS-slot DMA-pipelined core (kept for gv / y / out this round).
// ---------------------------------------------------------------------------
template <int BM, int BN, int IM, int IN, int NW, int NS>
__device__ __forceinline__ void gemm_core_p(
    const ushort_t* __restrict__ A, int lda,
    const ushort_t* __restrict__ B, int ldb,
    int K, int tile_m, int tile_n,
    ushort_t* buf,                    // NS * (BM+BN)*32 ushorts
    floatx4 (&acc)[IM][IN]) {

    constexpr int NT = NW * 64;
    constexpr int SA = BM * 4 / NT;
    constexpr int SB = BN * 4 / NT;
    constexpr int Q  = SA + SB;
    constexpr int SLOT = (BM + BN) * 32;
    constexpr int BOFF = BM * 32;

    const int tid  = threadIdx.x;
    const int lane = tid & 63;
    const int wave = tid >> 6;
    const int wm   = wave >> 1, wn = wave & 1;
    const int quad = lane >> 4;
    const int l16  = lane & 15;

#pragma unroll
    for (int i = 0; i < IM; i++)
#pragma unroll
        for (int j = 0; j < IN; j++) acc[i][j] = (floatx4){0.f, 0.f, 0.f, 0.f};

    const ushort_t* ga[SA];
    int la[SA];
#pragma unroll
    for (int s = 0; s < SA; s++) {
        int seg = tid + s * NT;
        int r = seg >> 2, c = (seg ^ r ^ (r >> 2)) & 3;
        ga[s] = A + (long)(r + tile_m) * lda + c * 8;
        la[s] = seg * 8;
    }
    const ushort_t* gb[SB];
    int lb[SB];
#pragma unroll
    for (int s = 0; s < SB; s++) {
        int seg = tid + s * NT;
        int r = seg >> 2, c = (seg ^ r ^ (r >> 2)) & 3;
        gb[s] = B + (long)(r + tile_n) * ldb + c * 8;
        lb[s] = BOFF + seg * 8;
    }

    const int nk = K >> 5;

#pragma unroll
    for (int p = 0; p < NS - 1; ++p) {
#pragma unroll
        for (int s = 0; s < SA; s++) async16(ga[s] + p * 32, buf + p * SLOT + la[s]);
#pragma unroll
        for (int s = 0; s < SB; s++) async16(gb[s] + p * 32, buf + p * SLOT + lb[s]);
    }

    int slot = 0, slot2 = NS - 1;
    for (int k = 0; k < nk; ++k) {
        const int rem = nk - 1 - k;
        if (rem >= NS - 2) {
            vwait<(NS - 2) * Q>();
        } else if (NS >= 4 && rem == 1) {
            vwait<Q>();
        } else {
            vwait<0>();
        }
        __builtin_amdgcn_s_barrier();
        asm volatile("" ::: "memory");

        if (k + NS - 1 < nk) {
            const int koff = (k + NS - 1) << 5;
            ushort_t* dst = buf + slot2 * SLOT;
#pragma unroll
            for (int s = 0; s < SA; s++) async16(ga[s] + koff, dst + la[s]);
#pragma unroll
            for (int s = 0; s < SB; s++) async16(gb[s] + koff, dst + lb[s]);
        }

        const ushort_t* as = buf + slot * SLOT;
        const ushort_t* bs = as + BOFF;
        bf16x8 af[IM], bfr[IN];
#pragma unroll
        for (int im = 0; im < IM; im++)
            af[im] = *(const bf16x8*)&as[sw(wm * IM * 16 + im * 16 + l16, quad)];
#pragma unroll
        for (int in = 0; in < IN; in++)
            bfr[in] = *(const bf16x8*)&bs[sw(wn * IN * 16 + in * 16 + l16, quad)];
#pragma unroll
        for (int im = 0; im < IM; im++)
#pragma unroll
            for (int in = 0; in < IN; in++)
                acc[im][in] = __builtin_amdgcn_mfma_f32_16x16x32_bf16(
                    af[im], bfr[in], acc[im][in], 0, 0, 0);

        slot  = (slot == NS - 1) ? 0 : slot + 1;
        slot2 = (slot2 == NS - 1) ? 0 : slot2 + 1;
    }
}

// ---------------------------------------------------------------------------
// 256x256 / BK=64 / 8-wave 8-phase core (T2+T3+T4+T5 template).
// Waves: (wm 0..1) x (wn 0..3); per-wave C = 128x64 = acc[8][4] frags.
// LDS: 2 tile-buffers x {A0,A1,B0,B1} halves, half = 128 rows x 64 cols bf16
//   region (ushorts): par*32768 + {A: h*8192 | B: 16384 + h*8192} + row*64
//   read swizzle: 16B-slot = (kk*4+quad) ^ (row&7)  -> 2 lanes/slot, conflict-free
//   staged via pre-swizzled GLOBAL source, linear LDS dest (global_load_lds rule).
// Phases per tile t (snake (0,0)(0,1)(1,1)(1,0); B fc0-1 kept in regs for ph4):
//   ph1: stage (t+1).A1 ; read A fr0-3, B fc0-1 ; bar ; 16 MFMA ; bar
//   ph2:                  read B fc2-3          ; bar ; 16 MFMA ; bar
//   ph3: stage (t+2).B0 ; read A fr4-7          ; bar ; 16 MFMA ; bar
//   ph4: stage (t+2).B1 + (t+2).A0              ; bar ; 16 MFMA ; vmcnt(6) ; bar
// Every stage lands on a region whose last LDS read was >=1 end-barrier earlier.
// Steady state: 3 half-tiles (6 loads) in flight across the tile boundary.
// ---------------------------------------------------------------------------
__device__ __forceinline__ void gemm256_8ph(
    const ushort_t* __restrict__ A, int lda,
    const ushort_t* __restrict__ B, int ldb,
    int K, int tile_m, int tile_n,
    ushort_t* buf,                      // 65536 ushorts = 128 KB
    floatx4 (&acc)[8][4]) {

    const int tid  = threadIdx.x;
    const int lane = tid & 63;
    const int wave = tid >> 6;          // 0..7
    const int wm   = wave >> 2;         // 0..1
    const int wn   = wave & 3;          // 0..3
    const int quad = lane >> 4;
    const int l16  = lane & 15;

#pragma unroll
    for (int i = 0; i < 8; i++)
#pragma unroll
        for (int j = 0; j < 4; j++) acc[i][j] = (floatx4){0.f, 0.f, 0.f, 0.f};

    // staging: thread tid -> row (tid>>3) of the 64-row instr block, slot tid&7.
    // LDS slot s of row r holds global col-group s ^ (r&7)  (involution).
    const int srow = tid >> 3;                     // 0..63
    const int scg  = (tid & 7) ^ (srow & 7);
    const ushort_t* gA = A + (long)(tile_m + srow) * lda + scg * 8;
    const ushort_t* gB = B + (long)(tile_n + srow) * ldb + scg * 8;
    ushort_t* const ld = buf + tid * 8;

#define STA_(p, h, t)                                                          \
    do {                                                                       \
        async16(gA + (long)((h)*128)      * lda + (t)*64,                      \
                ld + (p)*32768 + (h)*8192);                                    \
        async16(gA + (long)((h)*128 + 64) * lda + (t)*64,                      \
                ld + (p)*32768 + (h)*8192 + 4096);                             \
    } while (0)
#define STB_(p, h, t)                                                          \
    do {                                                                       \
        async16(gB + (long)((h)*128)      * ldb + (t)*64,                      \
                ld + (p)*32768 + 16384 + (h)*8192);                            \
        async16(gB + (long)((h)*128 + 64) * ldb + (t)*64,                      \
                ld + (p)*32768 + 16384 + (h)*8192 + 4096);                     \
    } while (0)

    // per-lane read bases: row_part = l16*64 ; slot = (kk*4+quad)^(l16&7)
    const int rb0 = l16 * 64 + (((quad)     ^ (l16 & 7)) << 3);
    const int rb1 = l16 * 64 + (((quad + 4) ^ (l16 & 7)) << 3);
    const int abase = wm * 8192;                            // A half = wm
    const int bbase = 16384 + (wn >> 1) * 8192 + (wn & 1) * 4096; // B half = wn>>1

    const int nt = K >> 6;

    // prologue: t0 {A0,B0,B1,A1}, t1 {B0,B1,A0} -> wait leaves t1's 3 halves in flight
    STA_(0, 0, 0); STB_(0, 0, 0); STB_(0, 1, 0); STA_(0, 1, 0);
    STB_(1, 0, 1); STB_(1, 1, 1); STA_(1, 0, 1);
    asm volatile("s_waitcnt vmcnt(6)" ::: "memory");
    __builtin_amdgcn_s_barrier();
    asm volatile("" ::: "memory");

    bf16x8 aR[4][2], bKc[2][2], bCc[2][2];

    for (int t = 0; t < nt; ++t) {
        const int p  = t & 1;
        const int pn = p ^ 1;
        const ushort_t* sb = buf + p * 32768;

        // ---------------- phase 1: quadrant (0,0) ----------------
        if (t + 1 < nt) STA_(pn, 1, t + 1);
#pragma unroll
        for (int fr = 0; fr < 4; fr++) {
            aR[fr][0] = *(const bf16x8*)&sb[abase + fr * 1024 + rb0];
            aR[fr][1] = *(const bf16x8*)&sb[abase + fr * 1024 + rb1];
        }
#pragma unroll
        for (int fc = 0; fc < 2; fc++) {
            bKc[fc][0] = *(const bf16x8*)&sb[bbase + fc * 1024 + rb0];
            bKc[fc][1] = *(const bf16x8*)&sb[bbase + fc * 1024 + rb1];
        }
        asm volatile("" ::: "memory");
        __builtin_amdgcn_s_barrier();
        __builtin_amdgcn_s_setprio(1);
#pragma unroll
        for (int fr = 0; fr < 4; fr++)
#pragma unroll
            for (int fc = 0; fc < 2; fc++) {
                acc[fr][fc] = __builtin_amdgcn_mfma_f32_16x16x32_bf16(
                    aR[fr][0], bKc[fc][0], acc[fr][fc], 0, 0, 0);
                acc[fr][fc] = __builtin_amdgcn_mfma_f32_16x16x32_bf16(
                    aR[fr][1], bKc[fc][1], acc[fr][fc], 0, 0, 0);
            }
        __builtin_amdgcn_s_setprio(0);
        asm volatile("" ::: "memory");
        __builtin_amdgcn_s_barrier();
        asm volatile("" ::: "memory");

        // ---------------- phase 2: quadrant (0,1) ----------------
#pragma unroll
        for (int fc = 0; fc < 2; fc++) {
            bCc[fc][0] = *(const bf16x8*)&sb[bbase + (fc + 2) * 1024 + rb0];
            bCc[fc][1] = *(const bf16x8*)&sb[bbase + (fc + 2) * 1024 + rb1];
        }
        asm volatile("" ::: "memory");
        __builtin_amdgcn_s_barrier();
        __builtin_amdgcn_s_setprio(1);
#pragma unroll
        for (int fr = 0; fr < 4; fr++)
#pragma unroll
            for (int fc = 0; fc < 2; fc++) {
                acc[fr][fc + 2] = __builtin_amdgcn_mfma_f32_16x16x32_bf16(
                    aR[fr][0], bCc[fc][0], acc[fr][fc + 2], 0, 0, 0);
                acc[fr][fc + 2] = __builtin_amdgcn_mfma_f32_16x16x32_bf16(
                    aR[fr][1], bCc[fc][1], acc[fr][fc + 2], 0, 0, 0);
            }
        __builtin_amdgcn_s_setprio(0);
        asm volatile("" ::: "memory");
        __builtin_amdgcn_s_barrier();
        asm volatile("" ::: "memory");

        // ---------------- phase 3: quadrant (1,1) ----------------
        if (t + 2 < nt) STB_(p, 0, t + 2);
#pragma unroll
        for (int fr = 0; fr < 4; fr++) {
            aR[fr][0] = *(const bf16x8*)&sb[abase + (fr + 4) * 1024 + rb0];
            aR[fr][1] = *(const bf16x8*)&sb[abase + (fr + 4) * 1024 + rb1];
        }
        asm volatile("" ::: "memory");
        __builtin_amdgcn_s_barrier();
        __builtin_amdgcn_s_setprio(1);
#pragma unroll
        for (int fr = 0; fr < 4; fr++)
#pragma unroll
            for (int fc = 0; fc < 2; fc++) {
                acc[fr + 4][fc + 2] = __builtin_amdgcn_mfma_f32_16x16x32_bf16(
                    aR[fr][0], bCc[fc][0], acc[fr + 4][fc + 2], 0, 0, 0);
                acc[fr + 4][fc + 2] = __builtin_amdgcn_mfma_f32_16x16x32_bf16(
                    aR[fr][1], bCc[fc][1], acc[fr + 4][fc + 2], 0, 0, 0);
            }
        __builtin_amdgcn_s_setprio(0);
        asm volatile("" ::: "memory");
        __builtin_amdgcn_s_barrier();
        asm volatile("" ::: "memory");

        // ---------------- phase 4: quadrant (1,0) ----------------
        if (t + 2 < nt) { STB_(p, 1, t + 2); STA_(p, 0, t + 2); }
        asm volatile("" ::: "memory");
        __builtin_amdgcn_s_barrier();
        __builtin_amdgcn_s_setprio(1);
#pragma unroll
        for (int fr = 0; fr < 4; fr++)
#pragma unroll
            for (int fc = 0; fc < 2; fc++) {
                acc[fr + 4][fc] = __builtin_amdgcn_mfma_f32_16x16x32_bf16(
                    aR[fr][0], bKc[fc][0], acc[fr + 4][fc], 0, 0, 0);
                acc[fr + 4][fc] = __builtin_amdgcn_mfma_f32_16x16x32_bf16(
                    aR[fr][1], bKc[fc][1], acc[fr + 4][fc], 0, 0, 0);
            }
        __builtin_amdgcn_s_setprio(0);
        if (t + 2 < nt) vwait<6>();
        else            vwait<0>();
        __builtin_amdgcn_s_barrier();
        asm volatile("" ::: "memory");
    }
#undef STA_
#undef STB_
}

// ---------------------------------------------------------------------------
// prep: fp32->bf16 for x & W_v, zero lsum, transpose+cast Wq/Wk -> WqT/WkT
// ---------------------------------------------------------------------------
__global__ void prep_kernel(const float* __restrict__ x,
                            const float* __restrict__ wq,
                            const float* __restrict__ wk,
                            const float* __restrict__ wv,
                            ushort_t* __restrict__ xb,
                            ushort_t* __restrict__ wvb,
                            ushort_t* __restrict__ wqT,
                            ushort_t* __restrict__ wkT,
                            float* __restrict__ lsum) {
    const int bx = blockIdx.x;
    const int t = threadIdx.x;
    if (bx < 9216) {
        const float* src;
        ushort_t* dst;
        long g;
        if (bx < 8192) { src = x;  dst = xb;  g = ((long)bx * 256 + t) * 4; }
        else           { src = wv; dst = wvb; g = ((long)(bx - 8192) * 256 + t) * 4; }
        float4 v = *(const float4*)(src + g);
        ushort4 o;
        o.x = f2bf(v.x); o.y = f2bf(v.y); o.z = f2bf(v.z); o.w = f2bf(v.w);
        *(ushort4*)(dst + g) = o;
        return;
    }
    if (bx < 9224) {
        int idx = (bx - 9216) * 256 + t;  // [0,2048)
        ((float4*)lsum)[idx] = (float4){0.f, 0.f, 0.f, 0.f};
        return;
    }
    const int tt = bx - 9224;           // [0,512)
    const float* src = (tt >= 256) ? wk : wq;
    ushort_t* dst = (tt >= 256) ? wkT : wqT;
    const int id = tt & 255;
    const int h0 = (id >> 4) * 64, d0 = (id & 15) * 64;
    __shared__ ushort_t tile[64 * 80];
    {
        int i = t >> 2, cg = (t & 3) << 4;
        const float4* p = (const float4*)(src + (long)(h0 + i) * 1024 + d0 + cg);
#pragma unroll
        for (int k = 0; k < 4; k++) {
            float4 v = p[k];
            ushort_t* q = &tile[i * 80 + cg + k * 4];
            q[0] = f2bf(v.x); q[1] = f2bf(v.y); q[2] = f2bf(v.z); q[3] = f2bf(v.w);
        }
    }
    __syncthreads();
    {
        int j = t >> 2, ig = (t & 3) << 4;
        ushort_t tmp[16];
#pragma unroll
        for (int k = 0; k < 16; k++) tmp[k] = tile[(ig + k) * 80 + j];
        ushort_t* o = dst + (long)(d0 + j) * 1024 + h0 + ig;
        *(uint4*)o = ((uint4*)tmp)[0];
        *(uint4*)(o + 8) = ((uint4*)tmp)[1];
    }
}

// ---------------------------------------------------------------------------
// gv: blocks [0,32) -> G ; [32,288) -> V^T.  (legacy core, NS=3)
// ---------------------------------------------------------------------------
__global__ __launch_bounds__(512, 4) void gv_kernel(
    const ushort_t* __restrict__ wkT, const ushort_t* __restrict__ wqT,
    const ushort_t* __restrict__ wvb, const ushort_t* __restrict__ xb,
    ushort_t* __restrict__ Gb, ushort_t* __restrict__ VTb) {

    __shared__ __align__(16) ushort_t buf[3 * 384 * 32];

    const ushort_t *A, *B;
    ushort_t* C;
    int ldc, tile_m, tile_n;
    if (blockIdx.x < 32) {
        A = wkT; B = wqT; C = Gb; ldc = 1024;
        tile_m = (blockIdx.x >> 3) * 256;
        tile_n = (blockIdx.x & 7) * 128;
    } else {
        int id = blockIdx.x - 32;
        A = wvb; B = xb; C = VTb; ldc = 8192;
        tile_m = (id >> 6) * 256;
        tile_n = (id & 63) * 128;
    }

    floatx4 acc[4][4];
    gemm_core_p<256, 128, 4, 4, 8, 3>(A, 1024, B, 1024, 1024, tile_m, tile_n, buf, acc);

    const int lane = threadIdx.x & 63, wave = threadIdx.x >> 6;
    const int wm = wave >> 1, wn = wave & 1, quad = lane >> 4, l16 = lane & 15;
#pragma unroll
    for (int im = 0; im < 4; im++)
#pragma unroll
        for (int r = 0; r < 4; r++) {
            int row = tile_m + wm * 64 + im * 16 + quad * 4 + r;
#pragma unroll
            for (int in = 0; in < 4; in++) {
                int col = tile_n + wn * 64 + in * 16 + l16;
                C[(long)row * ldc + col] = f2bf(acc[im][in][r]);
            }
        }
}

// ---------------------------------------------------------------------------
// Y = x G^T  (128x128 tiles, 512 blocks = 2/CU, NS=4, XCD swizzle)
// ---------------------------------------------------------------------------
__global__ __launch_bounds__(256) void y_kernel(
    const ushort_t* __restrict__ xb,
    const ushort_t* __restrict__ Gb,
    ushort_t* __restrict__ Yb) {

    __shared__ __align__(16) ushort_t buf[4 * 256 * 32];
    const int lin = xcd_swz(blockIdx.x, 64);   // 512 blocks
    const int tile_n = (lin & 7) * 128;
    const int tile_m = (lin >> 3) * 128;

    floatx4 acc[4][4];
    gemm_core_p<128, 128, 4, 4, 4, 4>(xb, 1024, Gb, 1024, 1024, tile_m, tile_n, buf, acc);

    const int lane = threadIdx.x & 63, wave = threadIdx.x >> 6;
    const int wm = wave >> 1, wn = wave & 1, quad = lane >> 4, l16 = lane & 15;
#pragma unroll
    for (int im = 0; im < 4; im++)
#pragma unroll
        for (int r = 0; r < 4; r++) {
            int row = tile_m + wm * 64 + im * 16 + quad * 4 + r;
#pragma unroll
            for (int in = 0; in < 4; in++) {
                int col = tile_n + wn * 64 + in * 16 + l16;
                Yb[(long)row * 1024 + col] = f2bf(acc[im][in][r]);
            }
        }
}

// ---------------------------------------------------------------------------
// P = exp(scale * Y x^T) per batch + fused row-sum atomics.
// NEW: 256x256 8-phase core, 256 blocks = 1/CU, 128 KB LDS, 8 waves.
// ---------------------------------------------------------------------------
__global__ __launch_bounds__(512, 2) void pexp_kernel(
    const ushort_t* __restrict__ Yb,
    const ushort_t* __restrict__ xb,
    ushort_t* __restrict__ Pb,
    float* __restrict__ lsum) {

    __shared__ __align__(16) ushort_t buf[65536];   // 128 KB

    const int lin = xcd_swz(blockIdx.x, 32);   // 256 blocks, bijective
    const int z = lin >> 6;                    // batch
    const int tile_m = ((lin >> 3) & 7) * 256; // 8 m-tiles
    const int tile_n = (lin & 7) * 256;        // 8 n-tiles

    const ushort_t* A = Yb + (long)z * 2097152;
    const ushort_t* B = xb + (long)z * 2097152;
    ushort_t* C = Pb + (long)z * 4194304;
    float* l = lsum + z * 2048;

    floatx4 acc[8][4];
    gemm256_8ph(A, 1024, B, 1024, 1024, tile_m, tile_n, buf, acc);

    const float scale = 0.022097086912079608f;  // 1/sqrt(2048)
    const int lane = threadIdx.x & 63, wave = threadIdx.x >> 6;
    const int wm = wave >> 2, wn = wave & 3, quad = lane >> 4, l16 = lane & 15;
#pragma unroll
    for (int fr = 0; fr < 8; fr++)
#pragma unroll
        for (int rr = 0; rr < 4; rr++) {
            int row = tile_m + wm * 128 + fr * 16 + quad * 4 + rr;
            float psum = 0.f;
#pragma unroll
            for (int fc = 0; fc < 4; fc++) {
                int col = tile_n + wn * 64 + fc * 16 + l16;
                float e = __expf(acc[fr][fc][rr] * scale);
                C[(long)row * 2048 + col] = f2bf(e);
                psum += e;
            }
            psum += __shfl_xor(psum, 1, 64);
            psum += __shfl_xor(psum, 2, 64);
            psum += __shfl_xor(psum, 4, 64);
            psum += __shfl_xor(psum, 8, 64);
            if (l16 == 0) atomicAdd(&l[row], psum);
        }
}

// ---------------------------------------------------------------------------
// out = (P V) / l per batch  (128x128 tiles, 512 blocks = 2/CU, NS=4)
// ---------------------------------------------------------------------------
__global__ __launch_bounds__(256) void out_kernel(
    const ushort_t* __restrict__ Pb,
    const ushort_t* __restrict__ VTb,
    float* __restrict__ out,
    const float* __restrict__ lsum) {

    __shared__ __align__(16) ushort_t buf[4 * 256 * 32];

    const int lin = xcd_swz(blockIdx.x, 64);   // 512 blocks
    const int z = lin >> 7;
    const int tile_m = ((lin >> 3) & 15) * 128;
    const int tile_n = (lin & 7) * 128;

    const ushort_t* A = Pb + (long)z * 4194304;
    const ushort_t* B = VTb + (long)z * 2048;
    float* C = out + (long)z * 2097152;
    const float* l = lsum + z * 2048;

    floatx4 acc[4][4];
    gemm_core_p<128, 128, 4, 4, 4, 4>(A, 2048, B, 8192, 2048, tile_m, tile_n, buf, acc);

    const int lane = threadIdx.x & 63, wave = threadIdx.x >> 6;
    const int wm = wave >> 1, wn = wave & 1, quad = lane >> 4, l16 = lane & 15;
#pragma unroll
    for (int im = 0; im < 4; im++)
#pragma unroll
        for (int r = 0; r < 4; r++) {
            int row = tile_m + wm * 64 + im * 16 + quad * 4 + r;
            float li = 1.0f / l[row];
#pragma unroll
            for (int in = 0; in < 4; in++) {
                int col = tile_n + wn * 64 + in * 16 + l16;
                C[(long)row * 1024 + col] = acc[im][in][r] * li;
            }
        }
}

// ---------------------------------------------------------------------------
extern "C" void kernel_launch(void* const* d_in, const int* in_sizes, int n_in,
                              void* d_out, int out_size, void* d_ws, size_t ws_size,
                              hipStream_t stream) {
    const float* x  = (const float*)d_in[0];
    const float* wq = (const float*)d_in[1];
    const float* wk = (const float*)d_in[2];
    const float* wv = (const float*)d_in[3];

    ushort_t* xb  = (ushort_t*)d_ws;          // [8192,1024] bf16
    ushort_t* wvb = xb  + 8388608;            // [1024,1024]
    ushort_t* wqT = wvb + 1048576;            // [1024,1024]
    ushort_t* wkT = wqT + 1048576;            // [1024,1024]
    ushort_t* Gb  = wkT + 1048576;            // [1024,1024]
    ushort_t* Yb  = Gb  + 1048576;            // [8192,1024]
    ushort_t* VTb = Yb  + 8388608;            // [1024,8192]
    ushort_t* Pb  = VTb + 8388608;            // [4][2048][2048]
    float*    lsum = (float*)(Pb + 16777216); // [4][2048]
    float*    out  = (float*)d_out;

    prep_kernel<<<9736, 256, 0, stream>>>(x, wq, wk, wv, xb, wvb, wqT, wkT, lsum);
    gv_kernel<<<288, 512, 0, stream>>>(wkT, wqT, wvb, xb, Gb, VTb);
    y_kernel<<<512, 256, 0, stream>>>(xb, Gb, Yb);
    pexp_kernel<<<256, 512, 0, stream>>>(Yb, xb, Pb, lsum);
    out_kernel<<<512, 256, 0, stream>>>(Pb, VTb, out, lsum);
}

// Round 3
// 230.378 us; speedup vs baseline: 1.0024x; 1.0024x over previous
//
#include <hip/hip_runtime.h>

typedef unsigned short ushort_t;
typedef __attribute__((ext_vector_type(8))) __bf16 bf16x8;
typedef __attribute__((ext_vector_type(4))) float floatx4;

__device__ __forceinline__ ushort_t f2bf(float f) {
    unsigned int u = __builtin_bit_cast(unsigned int, f);
    u = (u + 0x7fffu + ((u >> 16) & 1u)) >> 16;
    return (ushort_t)u;
}

__device__ __forceinline__ void async16(const ushort_t* g, ushort_t* l) {
    __builtin_amdgcn_global_load_lds(
        (const __attribute__((address_space(1))) unsigned int*)g,
        (__attribute__((address_space(3))) unsigned int*)l,
        16 /*bytes*/, 0 /*offset*/, 0 /*aux*/);
}

// XOR-swizzled LDS offset (ushort index) of the 8-elem group (row, cg) (legacy core).
__device__ __forceinline__ int sw(int row, int cg) {
    return ((row << 2) + ((cg ^ row ^ (row >> 2)) & 3)) << 3;
}

// XCD-chunked bijective blockIdx swizzle (nwg % 8 == 0).
__device__ __forceinline__ int xcd_swz(int bid, int cpx) {
    return (bid & 7) * cpx + (bid >> 3);
}

template <int N>
__device__ __forceinline__ void vwait() {   // legacy core only (keeps clobber)
    if constexpr (N == 0)      asm volatile("s_waitcnt vmcnt(0)" ::: "memory");
    else if constexpr (N == 3) asm volatile("s_waitcnt vmcnt(3)" ::: "memory");
    else if constexpr (N == 4) asm volatile("s_waitcnt vmcnt(4)" ::: "memory");
    else if constexpr (N == 6) asm volatile("s_waitcnt vmcnt(6)" ::: "memory");
    else if constexpr (N == 8) asm volatile("s_waitcnt vmcnt(8)" ::: "memory");
    else static_assert(N == 0, "unsupported vmcnt");
}

#define SBAR0() __builtin_amdgcn_sched_barrier(0)

// ---------------------------------------------------------------------------
// Legacy NS-slot DMA-pipelined core (kept for gv only).
// ---------------------------------------------------------------------------
template <int BM, int BN, int IM, int IN, int NW, int NS>
__device__ __forceinline__ void gemm_core_p(
    const ushort_t* __restrict__ A, int lda,
    const ushort_t* __restrict__ B, int ldb,
    int K, int tile_m, int tile_n,
    ushort_t* buf,                    // NS * (BM+BN)*32 ushorts
    floatx4 (&acc)[IM][IN]) {

    constexpr int NT = NW * 64;
    constexpr int SA = BM * 4 / NT;
    constexpr int SB = BN * 4 / NT;
    constexpr int Q  = SA + SB;
    constexpr int SLOT = (BM + BN) * 32;
    constexpr int BOFF = BM * 32;

    const int tid  = threadIdx.x;
    const int lane = tid & 63;
    const int wave = tid >> 6;
    const int wm   = wave >> 1, wn = wave & 1;
    const int quad = lane >> 4;
    const int l16  = lane & 15;

#pragma unroll
    for (int i = 0; i < IM; i++)
#pragma unroll
        for (int j = 0; j < IN; j++) acc[i][j] = (floatx4){0.f, 0.f, 0.f, 0.f};

    const ushort_t* ga[SA];
    int la[SA];
#pragma unroll
    for (int s = 0; s < SA; s++) {
        int seg = tid + s * NT;
        int r = seg >> 2, c = (seg ^ r ^ (r >> 2)) & 3;
        ga[s] = A + (long)(r + tile_m) * lda + c * 8;
        la[s] = seg * 8;
    }
    const ushort_t* gb[SB];
    int lb[SB];
#pragma unroll
    for (int s = 0; s < SB; s++) {
        int seg = tid + s * NT;
        int r = seg >> 2, c = (seg ^ r ^ (r >> 2)) & 3;
        gb[s] = B + (long)(r + tile_n) * ldb + c * 8;
        lb[s] = BOFF + seg * 8;
    }

    const int nk = K >> 5;

#pragma unroll
    for (int p = 0; p < NS - 1; ++p) {
#pragma unroll
        for (int s = 0; s < SA; s++) async16(ga[s] + p * 32, buf + p * SLOT + la[s]);
#pragma unroll
        for (int s = 0; s < SB; s++) async16(gb[s] + p * 32, buf + p * SLOT + lb[s]);
    }

    int slot = 0, slot2 = NS - 1;
    for (int k = 0; k < nk; ++k) {
        const int rem = nk - 1 - k;
        if (rem >= NS - 2) {
            vwait<(NS - 2) * Q>();
        } else if (NS >= 4 && rem == 1) {
            vwait<Q>();
        } else {
            vwait<0>();
        }
        __builtin_amdgcn_s_barrier();
        asm volatile("" ::: "memory");

        if (k + NS - 1 < nk) {
            const int koff = (k + NS - 1) << 5;
            ushort_t* dst = buf + slot2 * SLOT;
#pragma unroll
            for (int s = 0; s < SA; s++) async16(ga[s] + koff, dst + la[s]);
#pragma unroll
            for (int s = 0; s < SB; s++) async16(gb[s] + koff, dst + lb[s]);
        }

        const ushort_t* as = buf + slot * SLOT;
        const ushort_t* bs = as + BOFF;
        bf16x8 af[IM], bfr[IN];
#pragma unroll
        for (int im = 0; im < IM; im++)
            af[im] = *(const bf16x8*)&as[sw(wm * IM * 16 + im * 16 + l16, quad)];
#pragma unroll
        for (int in = 0; in < IN; in++)
            bfr[in] = *(const bf16x8*)&bs[sw(wn * IN * 16 + in * 16 + l16, quad)];
#pragma unroll
        for (int im = 0; im < IM; im++)
#pragma unroll
            for (int in = 0; in < IN; in++)
                acc[im][in] = __builtin_amdgcn_mfma_f32_16x16x32_bf16(
                    af[im], bfr[in], acc[im][in], 0, 0, 0);

        slot  = (slot == NS - 1) ? 0 : slot + 1;
        slot2 = (slot2 == NS - 1) ? 0 : slot2 + 1;
    }
}

// ---------------------------------------------------------------------------
// 256x256 / BK=64 / 8-wave 8-phase core, v2: de-clobbered (bare waitcnt asm,
// sched_barrier(0) ordering fences only). Waves (wm 0..1)x(wn 0..3), per-wave
// C = 128x64 = acc[8][4]. LDS 128 KB = 2 parities x {A0,A1,B0,B1} 16 KB halves.
// Read swizzle: 16B-slot = (kk*4+quad)^(row&7); staged via pre-swizzled global
// source + linear LDS dest. Phases (snake (0,0)(0,1)(1,1)(1,0); bKc lives
// ph1->ph4 in regs):
//   ph1: read A fr0-3 + B fc0-1 ; stage (t+1).A1 ; lgkmcnt(8)
//   ph2: read B fc2-3
//   ph3: read A fr4-7 ; stage (t+2).B0
//   ph4: stage (t+2).B1 + (t+2).A0 ; vmcnt(6) after MFMA (once per K-tile)
// Region-hazard audit: every stage targets a region whose last ds_read
// completed before a preceding end-barrier (cross-wave safe).
// ---------------------------------------------------------------------------
__device__ __forceinline__ void gemm256_8ph(
    const ushort_t* __restrict__ A, int lda,
    const ushort_t* __restrict__ B, int ldb,
    int K, int tile_m, int tile_n,
    ushort_t* buf,                      // 65536 ushorts = 128 KB
    floatx4 (&acc)[8][4]) {

    const int tid  = threadIdx.x;
    const int lane = tid & 63;
    const int wave = tid >> 6;
    const int wm   = wave >> 2;
    const int wn   = wave & 3;
    const int quad = lane >> 4;
    const int l16  = lane & 15;

#pragma unroll
    for (int i = 0; i < 8; i++)
#pragma unroll
        for (int j = 0; j < 4; j++) acc[i][j] = (floatx4){0.f, 0.f, 0.f, 0.f};

    const int srow = tid >> 3;                     // 0..63
    const int scg  = (tid & 7) ^ (srow & 7);
    const ushort_t* gA = A + (long)(tile_m + srow) * lda + scg * 8;
    const ushort_t* gB = B + (long)(tile_n + srow) * ldb + scg * 8;
    ushort_t* const ld = buf + tid * 8;

#define STA_(p, h, t)                                                          \
    do {                                                                       \
        async16(gA + (long)((h)*128)      * lda + (t)*64,                      \
                ld + (p)*32768 + (h)*8192);                                    \
        async16(gA + (long)((h)*128 + 64) * lda + (t)*64,                      \
                ld + (p)*32768 + (h)*8192 + 4096);                             \
    } while (0)
#define STB_(p, h, t)                                                          \
    do {                                                                       \
        async16(gB + (long)((h)*128)      * ldb + (t)*64,                      \
                ld + (p)*32768 + 16384 + (h)*8192);                            \
        async16(gB + (long)((h)*128 + 64) * ldb + (t)*64,                      \
                ld + (p)*32768 + 16384 + (h)*8192 + 4096);                     \
    } while (0)

    const int rb0 = l16 * 64 + (((quad)     ^ (l16 & 7)) << 3);
    const int rb1 = l16 * 64 + (((quad + 4) ^ (l16 & 7)) << 3);
    const int abase = wm * 8192;
    const int bbase = 16384 + (wn >> 1) * 8192 + (wn & 1) * 4096;

    const int nt = K >> 6;

    // prologue: t0 {A0,B0,B1,A1}, t1 {B0,B1,A0}
    STA_(0, 0, 0); STB_(0, 0, 0); STB_(0, 1, 0); STA_(0, 1, 0);
    STB_(1, 0, 1); STB_(1, 1, 1); STA_(1, 0, 1);
    asm volatile("s_waitcnt vmcnt(6)");
    SBAR0();
    __builtin_amdgcn_s_barrier();
    SBAR0();

    bf16x8 aR[4][2], bKc[2][2], bCc[2][2];

    for (int t = 0; t < nt; ++t) {
        const int p  = t & 1;
        const int pn = p ^ 1;
        const ushort_t* sb = buf + p * 32768;

        // ---------------- phase 1: quadrant (0,0) ----------------
#pragma unroll
        for (int fr = 0; fr < 4; fr++) {
            aR[fr][0] = *(const bf16x8*)&sb[abase + fr * 1024 + rb0];
            aR[fr][1] = *(const bf16x8*)&sb[abase + fr * 1024 + rb1];
        }
#pragma unroll
        for (int fc = 0; fc < 2; fc++) {
            bKc[fc][0] = *(const bf16x8*)&sb[bbase + fc * 1024 + rb0];
            bKc[fc][1] = *(const bf16x8*)&sb[bbase + fc * 1024 + rb1];
        }
        if (t + 1 < nt) STA_(pn, 1, t + 1);
        asm volatile("s_waitcnt lgkmcnt(8)");
        SBAR0();
        __builtin_amdgcn_s_barrier();
        asm volatile("s_waitcnt lgkmcnt(0)");
        SBAR0();
        __builtin_amdgcn_s_setprio(1);
#pragma unroll
        for (int fr = 0; fr < 4; fr++)
#pragma unroll
            for (int fc = 0; fc < 2; fc++) {
                acc[fr][fc] = __builtin_amdgcn_mfma_f32_16x16x32_bf16(
                    aR[fr][0], bKc[fc][0], acc[fr][fc], 0, 0, 0);
                acc[fr][fc] = __builtin_amdgcn_mfma_f32_16x16x32_bf16(
                    aR[fr][1], bKc[fc][1], acc[fr][fc], 0, 0, 0);
            }
        __builtin_amdgcn_s_setprio(0);
        SBAR0();
        __builtin_amdgcn_s_barrier();
        SBAR0();

        // ---------------- phase 2: quadrant (0,1) ----------------
#pragma unroll
        for (int fc = 0; fc < 2; fc++) {
            bCc[fc][0] = *(const bf16x8*)&sb[bbase + (fc + 2) * 1024 + rb0];
            bCc[fc][1] = *(const bf16x8*)&sb[bbase + (fc + 2) * 1024 + rb1];
        }
        SBAR0();
        __builtin_amdgcn_s_barrier();
        asm volatile("s_waitcnt lgkmcnt(0)");
        SBAR0();
        __builtin_amdgcn_s_setprio(1);
#pragma unroll
        for (int fr = 0; fr < 4; fr++)
#pragma unroll
            for (int fc = 0; fc < 2; fc++) {
                acc[fr][fc + 2] = __builtin_amdgcn_mfma_f32_16x16x32_bf16(
                    aR[fr][0], bCc[fc][0], acc[fr][fc + 2], 0, 0, 0);
                acc[fr][fc + 2] = __builtin_amdgcn_mfma_f32_16x16x32_bf16(
                    aR[fr][1], bCc[fc][1], acc[fr][fc + 2], 0, 0, 0);
            }
        __builtin_amdgcn_s_setprio(0);
        SBAR0();
        __builtin_amdgcn_s_barrier();
        SBAR0();

        // ---------------- phase 3: quadrant (1,1) ----------------
#pragma unroll
        for (int fr = 0; fr < 4; fr++) {
            aR[fr][0] = *(const bf16x8*)&sb[abase + (fr + 4) * 1024 + rb0];
            aR[fr][1] = *(const bf16x8*)&sb[abase + (fr + 4) * 1024 + rb1];
        }
        if (t + 2 < nt) STB_(p, 0, t + 2);
        SBAR0();
        __builtin_amdgcn_s_barrier();
        asm volatile("s_waitcnt lgkmcnt(0)");
        SBAR0();
        __builtin_amdgcn_s_setprio(1);
#pragma unroll
        for (int fr = 0; fr < 4; fr++)
#pragma unroll
            for (int fc = 0; fc < 2; fc++) {
                acc[fr + 4][fc + 2] = __builtin_amdgcn_mfma_f32_16x16x32_bf16(
                    aR[fr][0], bCc[fc][0], acc[fr + 4][fc + 2], 0, 0, 0);
                acc[fr + 4][fc + 2] = __builtin_amdgcn_mfma_f32_16x16x32_bf16(
                    aR[fr][1], bCc[fc][1], acc[fr + 4][fc + 2], 0, 0, 0);
            }
        __builtin_amdgcn_s_setprio(0);
        SBAR0();
        __builtin_amdgcn_s_barrier();
        SBAR0();

        // ---------------- phase 4: quadrant (1,0) ----------------
        if (t + 2 < nt) { STB_(p, 1, t + 2); STA_(p, 0, t + 2); }
        SBAR0();
        __builtin_amdgcn_s_barrier();
        SBAR0();
        __builtin_amdgcn_s_setprio(1);
#pragma unroll
        for (int fr = 0; fr < 4; fr++)
#pragma unroll
            for (int fc = 0; fc < 2; fc++) {
                acc[fr + 4][fc] = __builtin_amdgcn_mfma_f32_16x16x32_bf16(
                    aR[fr][0], bKc[fc][0], acc[fr + 4][fc], 0, 0, 0);
                acc[fr + 4][fc] = __builtin_amdgcn_mfma_f32_16x16x32_bf16(
                    aR[fr][1], bKc[fc][1], acc[fr + 4][fc], 0, 0, 0);
            }
        __builtin_amdgcn_s_setprio(0);
        if (t + 2 < nt) asm volatile("s_waitcnt vmcnt(6)");
        else            asm volatile("s_waitcnt vmcnt(0)");
        SBAR0();
        __builtin_amdgcn_s_barrier();
        SBAR0();
    }
#undef STA_
#undef STB_
}

// ---------------------------------------------------------------------------
// 128x256 / BK=64 / 8-wave counted-vmcnt 2-phase core (96 KB LDS, 1 block/CU).
// Waves (wm 0..1)x(wn 0..3), per-wave C = 64x64 = acc[4][4].
// LDS per parity (24576 ushorts): A[128x64] @0, B[256x64] @8192.
// B is fc-MAJOR: B row = fc*64 + wn*16 + l16, so ph1 reads only B rows 0-127
// (unit B0) and ph2 reads only rows 128-255 (unit B1) -> stage targets never
// collide with same-phase reads.
// Stage schedule: ph1 of t: (t+1).B1 ; ph2 of t: (t+2).A + (t+2).B0.
// Waits: ph1-end vmcnt(6) [drains (t).B1 pre-ph2-reads];
//        ph2-end vmcnt(6) [drains (t+1).A,B0 pre-next-ph1-reads]. Never 0
// in steady state; every unit gets >=2 phases of flight.
// ---------------------------------------------------------------------------
__device__ __forceinline__ void gemm_bn256_2ph(
    const ushort_t* __restrict__ A, int lda,
    const ushort_t* __restrict__ B, int ldb,
    int K, int tile_m, int tile_n,
    ushort_t* buf,                      // 49152 ushorts = 96 KB
    floatx4 (&acc)[4][4]) {

    const int tid  = threadIdx.x;
    const int lane = tid & 63;
    const int wave = tid >> 6;
    const int wm   = wave >> 2;
    const int wn   = wave & 3;
    const int quad = lane >> 4;
    const int l16  = lane & 15;

#pragma unroll
    for (int i = 0; i < 4; i++)
#pragma unroll
        for (int j = 0; j < 4; j++) acc[i][j] = (floatx4){0.f, 0.f, 0.f, 0.f};

    const int srow = tid >> 3;
    const int scg  = (tid & 7) ^ (srow & 7);
    const ushort_t* gA = A + (long)(tile_m + srow) * lda + scg * 8;
    const ushort_t* gB = B + (long)(tile_n + srow) * ldb + scg * 8;
    ushort_t* const ld = buf + tid * 8;

#define SAU_(p, t)                                                             \
    do {                                                                       \
        async16(gA + (long)(t)*64,            ld + (p)*24576);                 \
        async16(gA + (long)64*lda  + (t)*64,  ld + (p)*24576 + 4096);          \
    } while (0)
#define SB0_(p, t)                                                             \
    do {                                                                       \
        async16(gB + (long)(t)*64,            ld + (p)*24576 + 8192);          \
        async16(gB + (long)64*ldb  + (t)*64,  ld + (p)*24576 + 12288);         \
    } while (0)
#define SB1_(p, t)                                                             \
    do {                                                                       \
        async16(gB + (long)128*ldb + (t)*64,  ld + (p)*24576 + 16384);         \
        async16(gB + (long)192*ldb + (t)*64,  ld + (p)*24576 + 20480);         \
    } while (0)

    const int rb0 = l16 * 64 + (((quad)     ^ (l16 & 7)) << 3);
    const int rb1 = l16 * 64 + (((quad + 4) ^ (l16 & 7)) << 3);
    const int ab = wm * 4096;                 // A row = wm*64 + fr*16 + l16
    const int bb = 8192 + wn * 1024;          // B row = fc*64 + wn*16 + l16

    const int nt = K >> 6;

    // prologue: t0 {A,B0,B1}, t1 {A,B0}
    SAU_(0, 0); SB0_(0, 0); SB1_(0, 0);
    SAU_(1, 1); SB0_(1, 1);
    asm volatile("s_waitcnt vmcnt(4)");
    SBAR0();
    __builtin_amdgcn_s_barrier();
    SBAR0();

    bf16x8 aR[4][2], bKc[2][2], bCc[2][2];

    for (int t = 0; t < nt; ++t) {
        const int p  = t & 1;
        const int pn = p ^ 1;
        const ushort_t* sb = buf + p * 24576;

        // ---------------- phase 1: fc 0-1 (B rows 0-127 = unit B0) ----------
#pragma unroll
        for (int fr = 0; fr < 4; fr++) {
            aR[fr][0] = *(const bf16x8*)&sb[ab + fr * 1024 + rb0];
            aR[fr][1] = *(const bf16x8*)&sb[ab + fr * 1024 + rb1];
        }
#pragma unroll
        for (int fc = 0; fc < 2; fc++) {
            bKc[fc][0] = *(const bf16x8*)&sb[bb + fc * 4096 + rb0];
            bKc[fc][1] = *(const bf16x8*)&sb[bb + fc * 4096 + rb1];
        }
        if (t + 1 < nt) SB1_(pn, t + 1);
        asm volatile("s_waitcnt lgkmcnt(8)");
        SBAR0();
        __builtin_amdgcn_s_barrier();
        asm volatile("s_waitcnt lgkmcnt(0)");
        SBAR0();
        __builtin_amdgcn_s_setprio(1);
#pragma unroll
        for (int fr = 0; fr < 4; fr++)
#pragma unroll
            for (int fc = 0; fc < 2; fc++) {
                acc[fr][fc] = __builtin_amdgcn_mfma_f32_16x16x32_bf16(
                    aR[fr][0], bKc[fc][0], acc[fr][fc], 0, 0, 0);
                acc[fr][fc] = __builtin_amdgcn_mfma_f32_16x16x32_bf16(
                    aR[fr][1], bKc[fc][1], acc[fr][fc], 0, 0, 0);
            }
        __builtin_amdgcn_s_setprio(0);
        if (t + 1 < nt) asm volatile("s_waitcnt vmcnt(6)");
        else            asm volatile("s_waitcnt vmcnt(0)");
        SBAR0();
        __builtin_amdgcn_s_barrier();
        SBAR0();

        // ---------------- phase 2: fc 2-3 (B rows 128-255 = unit B1) --------
#pragma unroll
        for (int fc = 0; fc < 2; fc++) {
            bCc[fc][0] = *(const bf16x8*)&sb[bb + (fc + 2) * 4096 + rb0];
            bCc[fc][1] = *(const bf16x8*)&sb[bb + (fc + 2) * 4096 + rb1];
        }
        if (t + 2 < nt) { SAU_(p, t + 2); SB0_(p, t + 2); }
        SBAR0();
        __builtin_amdgcn_s_barrier();
        asm volatile("s_waitcnt lgkmcnt(0)");
        SBAR0();
        __builtin_amdgcn_s_setprio(1);
#pragma unroll
        for (int fr = 0; fr < 4; fr++)
#pragma unroll
            for (int fc = 0; fc < 2; fc++) {
                acc[fr][fc + 2] = __builtin_amdgcn_mfma_f32_16x16x32_bf16(
                    aR[fr][0], bCc[fc][0], acc[fr][fc + 2], 0, 0, 0);
                acc[fr][fc + 2] = __builtin_amdgcn_mfma_f32_16x16x32_bf16(
                    aR[fr][1], bCc[fc][1], acc[fr][fc + 2], 0, 0, 0);
            }
        __builtin_amdgcn_s_setprio(0);
        if (t + 2 < nt)      asm volatile("s_waitcnt vmcnt(6)");
        else if (t + 1 < nt) asm volatile("s_waitcnt vmcnt(2)");
        else                 asm volatile("s_waitcnt vmcnt(0)");
        SBAR0();
        __builtin_amdgcn_s_barrier();
        SBAR0();
    }
#undef SAU_
#undef SB0_
#undef SB1_
}

// ---------------------------------------------------------------------------
// prep: fp32->bf16 for x & W_v, zero lsum, transpose+cast Wq/Wk -> WqT/WkT
// ---------------------------------------------------------------------------
__global__ void prep_kernel(const float* __restrict__ x,
                            const float* __restrict__ wq,
                            const float* __restrict__ wk,
                            const float* __restrict__ wv,
                            ushort_t* __restrict__ xb,
                            ushort_t* __restrict__ wvb,
                            ushort_t* __restrict__ wqT,
                            ushort_t* __restrict__ wkT,
                            float* __restrict__ lsum) {
    const int bx = blockIdx.x;
    const int t = threadIdx.x;
    if (bx < 9216) {
        const float* src;
        ushort_t* dst;
        long g;
        if (bx < 8192) { src = x;  dst = xb;  g = ((long)bx * 256 + t) * 4; }
        else           { src = wv; dst = wvb; g = ((long)(bx - 8192) * 256 + t) * 4; }
        float4 v = *(const float4*)(src + g);
        ushort4 o;
        o.x = f2bf(v.x); o.y = f2bf(v.y); o.z = f2bf(v.z); o.w = f2bf(v.w);
        *(ushort4*)(dst + g) = o;
        return;
    }
    if (bx < 9224) {
        int idx = (bx - 9216) * 256 + t;  // [0,2048)
        ((float4*)lsum)[idx] = (float4){0.f, 0.f, 0.f, 0.f};
        return;
    }
    const int tt = bx - 9224;           // [0,512)
    const float* src = (tt >= 256) ? wk : wq;
    ushort_t* dst = (tt >= 256) ? wkT : wqT;
    const int id = tt & 255;
    const int h0 = (id >> 4) * 64, d0 = (id & 15) * 64;
    __shared__ ushort_t tile[64 * 80];
    {
        int i = t >> 2, cg = (t & 3) << 4;
        const float4* p = (const float4*)(src + (long)(h0 + i) * 1024 + d0 + cg);
#pragma unroll
        for (int k = 0; k < 4; k++) {
            float4 v = p[k];
            ushort_t* q = &tile[i * 80 + cg + k * 4];
            q[0] = f2bf(v.x); q[1] = f2bf(v.y); q[2] = f2bf(v.z); q[3] = f2bf(v.w);
        }
    }
    __syncthreads();
    {
        int j = t >> 2, ig = (t & 3) << 4;
        ushort_t tmp[16];
#pragma unroll
        for (int k = 0; k < 16; k++) tmp[k] = tile[(ig + k) * 80 + j];
        ushort_t* o = dst + (long)(d0 + j) * 1024 + h0 + ig;
        *(uint4*)o = ((uint4*)tmp)[0];
        *(uint4*)(o + 8) = ((uint4*)tmp)[1];
    }
}

// ---------------------------------------------------------------------------
// gv: blocks [0,32) -> G ; [32,288) -> V^T.  (legacy core, NS=3)
// ---------------------------------------------------------------------------
__global__ __launch_bounds__(512, 4) void gv_kernel(
    const ushort_t* __restrict__ wkT, const ushort_t* __restrict__ wqT,
    const ushort_t* __restrict__ wvb, const ushort_t* __restrict__ xb,
    ushort_t* __restrict__ Gb, ushort_t* __restrict__ VTb) {

    __shared__ __align__(16) ushort_t buf[3 * 384 * 32];

    const ushort_t *A, *B;
    ushort_t* C;
    int ldc, tile_m, tile_n;
    if (blockIdx.x < 32) {
        A = wkT; B = wqT; C = Gb; ldc = 1024;
        tile_m = (blockIdx.x >> 3) * 256;
        tile_n = (blockIdx.x & 7) * 128;
    } else {
        int id = blockIdx.x - 32;
        A = wvb; B = xb; C = VTb; ldc = 8192;
        tile_m = (id >> 6) * 256;
        tile_n = (id & 63) * 128;
    }

    floatx4 acc[4][4];
    gemm_core_p<256, 128, 4, 4, 8, 3>(A, 1024, B, 1024, 1024, tile_m, tile_n, buf, acc);

    const int lane = threadIdx.x & 63, wave = threadIdx.x >> 6;
    const int wm = wave >> 1, wn = wave & 1, quad = lane >> 4, l16 = lane & 15;
#pragma unroll
    for (int im = 0; im < 4; im++)
#pragma unroll
        for (int r = 0; r < 4; r++) {
            int row = tile_m + wm * 64 + im * 16 + quad * 4 + r;
#pragma unroll
            for (int in = 0; in < 4; in++) {
                int col = tile_n + wn * 64 + in * 16 + l16;
                C[(long)row * ldc + col] = f2bf(acc[im][in][r]);
            }
        }
}

// ---------------------------------------------------------------------------
// Y = x G^T  (M=8192, N=1024, K=1024; 128x256 tiles, 256 blocks = 1/CU)
// ---------------------------------------------------------------------------
__global__ __launch_bounds__(512, 2) void y_kernel(
    const ushort_t* __restrict__ xb,
    const ushort_t* __restrict__ Gb,
    ushort_t* __restrict__ Yb) {

    __shared__ __align__(16) ushort_t buf[49152];   // 96 KB
    const int lin = xcd_swz(blockIdx.x, 32);        // 256 blocks
    const int tile_m = (lin >> 2) * 128;            // 64 m-tiles
    const int tile_n = (lin & 3) * 256;             // 4 n-tiles (fastest)

    floatx4 acc[4][4];
    gemm_bn256_2ph(xb, 1024, Gb, 1024, 1024, tile_m, tile_n, buf, acc);

    const int lane = threadIdx.x & 63, wave = threadIdx.x >> 6;
    const int wm = wave >> 2, wn = wave & 3, quad = lane >> 4, l16 = lane & 15;
#pragma unroll
    for (int fr = 0; fr < 4; fr++)
#pragma unroll
        for (int r = 0; r < 4; r++) {
            int row = tile_m + wm * 64 + fr * 16 + quad * 4 + r;
#pragma unroll
            for (int fc = 0; fc < 4; fc++) {
                int col = tile_n + fc * 64 + wn * 16 + l16;
                Yb[(long)row * 1024 + col] = f2bf(acc[fr][fc][r]);
            }
        }
}

// ---------------------------------------------------------------------------
// P = exp(scale * Y x^T) per batch + fused row-sum atomics.
// 256x256 8-phase v2 core, 256 blocks = 1/CU, 128 KB LDS, 8 waves.
// ---------------------------------------------------------------------------
__global__ __launch_bounds__(512, 2) void pexp_kernel(
    const ushort_t* __restrict__ Yb,
    const ushort_t* __restrict__ xb,
    ushort_t* __restrict__ Pb,
    float* __restrict__ lsum) {

    __shared__ __align__(16) ushort_t buf[65536];   // 128 KB

    const int lin = xcd_swz(blockIdx.x, 32);   // 256 blocks, bijective
    const int z = lin >> 6;                    // batch
    const int tile_m = ((lin >> 3) & 7) * 256; // 8 m-tiles
    const int tile_n = (lin & 7) * 256;        // 8 n-tiles

    const ushort_t* A = Yb + (long)z * 2097152;
    const ushort_t* B = xb + (long)z * 2097152;
    ushort_t* C = Pb + (long)z * 4194304;
    float* l = lsum + z * 2048;

    floatx4 acc[8][4];
    gemm256_8ph(A, 1024, B, 1024, 1024, tile_m, tile_n, buf, acc);

    const float scale = 0.022097086912079608f;  // 1/sqrt(2048)
    const int lane = threadIdx.x & 63, wave = threadIdx.x >> 6;
    const int wm = wave >> 2, wn = wave & 3, quad = lane >> 4, l16 = lane & 15;
#pragma unroll
    for (int fr = 0; fr < 8; fr++)
#pragma unroll
        for (int rr = 0; rr < 4; rr++) {
            int row = tile_m + wm * 128 + fr * 16 + quad * 4 + rr;
            float psum = 0.f;
#pragma unroll
            for (int fc = 0; fc < 4; fc++) {
                int col = tile_n + wn * 64 + fc * 16 + l16;
                float e = __expf(acc[fr][fc][rr] * scale);
                C[(long)row * 2048 + col] = f2bf(e);
                psum += e;
            }
            psum += __shfl_xor(psum, 1, 64);
            psum += __shfl_xor(psum, 2, 64);
            psum += __shfl_xor(psum, 4, 64);
            psum += __shfl_xor(psum, 8, 64);
            if (l16 == 0) atomicAdd(&l[row], psum);
        }
}

// ---------------------------------------------------------------------------
// out = (P V) / l per batch  (128x256 tiles, K=2048, 256 blocks = 1/CU)
// ---------------------------------------------------------------------------
__global__ __launch_bounds__(512, 2) void out_kernel(
    const ushort_t* __restrict__ Pb,
    const ushort_t* __restrict__ VTb,
    float* __restrict__ out,
    const float* __restrict__ lsum) {

    __shared__ __align__(16) ushort_t buf[49152];   // 96 KB

    const int lin = xcd_swz(blockIdx.x, 32);   // 256 blocks
    const int z = lin >> 6;                    // batch
    const int tile_m = ((lin >> 2) & 15) * 128;// 16 m-tiles
    const int tile_n = (lin & 3) * 256;        // 4 n-tiles (fastest)

    const ushort_t* A = Pb + (long)z * 4194304;   // [2048][2048]
    const ushort_t* B = VTb + (long)z * 2048;     // ldb=8192, batch col slice
    float* C = out + (long)z * 2097152;
    const float* l = lsum + z * 2048;

    floatx4 acc[4][4];
    gemm_bn256_2ph(A, 2048, B, 8192, 2048, tile_m, tile_n, buf, acc);

    const int lane = threadIdx.x & 63, wave = threadIdx.x >> 6;
    const int wm = wave >> 2, wn = wave & 3, quad = lane >> 4, l16 = lane & 15;
#pragma unroll
    for (int fr = 0; fr < 4; fr++)
#pragma unroll
        for (int r = 0; r < 4; r++) {
            int row = tile_m + wm * 64 + fr * 16 + quad * 4 + r;
            float li = 1.0f / l[row];
#pragma unroll
            for (int fc = 0; fc < 4; fc++) {
                int col = tile_n + fc * 64 + wn * 16 + l16;
                C[(long)row * 1024 + col] = acc[fr][fc][r] * li;
            }
        }
}

// ---------------------------------------------------------------------------
extern "C" void kernel_launch(void* const* d_in, const int* in_sizes, int n_in,
                              void* d_out, int out_size, void* d_ws, size_t ws_size,
                              hipStream_t stream) {
    const float* x  = (const float*)d_in[0];
    const float* wq = (const float*)d_in[1];
    const float* wk = (const float*)d_in[2];
    const float* wv = (const float*)d_in[3];

    ushort_t* xb  = (ushort_t*)d_ws;          // [8192,1024] bf16
    ushort_t* wvb = xb  + 8388608;            // [1024,1024]
    ushort_t* wqT = wvb + 1048576;            // [1024,1024]
    ushort_t* wkT = wqT + 1048576;            // [1024,1024]
    ushort_t* Gb  = wkT + 1048576;            // [1024,1024]
    ushort_t* Yb  = Gb  + 1048576;            // [8192,1024]
    ushort_t* VTb = Yb  + 8388608;            // [1024,8192]
    ushort_t* Pb  = VTb + 8388608;            // [4][2048][2048]
    float*    lsum = (float*)(Pb + 16777216); // [4][2048]
    float*    out  = (float*)d_out;

    prep_kernel<<<9736, 256, 0, stream>>>(x, wq, wk, wv, xb, wvb, wqT, wkT, lsum);
    gv_kernel<<<288, 512, 0, stream>>>(wkT, wqT, wvb, xb, Gb, VTb);
    y_kernel<<<256, 512, 0, stream>>>(xb, Gb, Yb);
    pexp_kernel<<<256, 512, 0, stream>>>(Yb, xb, Pb, lsum);
    out_kernel<<<256, 512, 0, stream>>>(Pb, VTb, out, lsum);
}

// Round 4
// 229.140 us; speedup vs baseline: 1.0078x; 1.0054x over previous
//
#include <hip/hip_runtime.h>

typedef unsigned short ushort_t;
typedef __attribute__((ext_vector_type(8))) __bf16 bf16x8;
typedef __attribute__((ext_vector_type(4))) float floatx4;

__device__ __forceinline__ ushort_t f2bf(float f) {
    unsigned int u = __builtin_bit_cast(unsigned int, f);
    u = (u + 0x7fffu + ((u >> 16) & 1u)) >> 16;
    return (ushort_t)u;
}

__device__ __forceinline__ void async16(const ushort_t* g, ushort_t* l) {
    __builtin_amdgcn_global_load_lds(
        (const __attribute__((address_space(1))) unsigned int*)g,
        (__attribute__((address_space(3))) unsigned int*)l,
        16 /*bytes*/, 0 /*offset*/, 0 /*aux*/);
}

// XOR-swizzled LDS offset (ushort index) of the 8-elem group (row, cg) (legacy core).
__device__ __forceinline__ int sw(int row, int cg) {
    return ((row << 2) + ((cg ^ row ^ (row >> 2)) & 3)) << 3;
}

// XCD-chunked bijective blockIdx swizzle (nwg % 8 == 0).
__device__ __forceinline__ int xcd_swz(int bid, int cpx) {
    return (bid & 7) * cpx + (bid >> 3);
}

template <int N>
__device__ __forceinline__ void vwait() {   // legacy core only (keeps clobber)
    if constexpr (N == 0)      asm volatile("s_waitcnt vmcnt(0)" ::: "memory");
    else if constexpr (N == 3) asm volatile("s_waitcnt vmcnt(3)" ::: "memory");
    else if constexpr (N == 4) asm volatile("s_waitcnt vmcnt(4)" ::: "memory");
    else if constexpr (N == 6) asm volatile("s_waitcnt vmcnt(6)" ::: "memory");
    else if constexpr (N == 8) asm volatile("s_waitcnt vmcnt(8)" ::: "memory");
    else static_assert(N == 0, "unsupported vmcnt");
}

// ---------------------------------------------------------------------------
// Legacy NS-slot DMA-pipelined core (kept for gv only).
// ---------------------------------------------------------------------------
template <int BM, int BN, int IM, int IN, int NW, int NS>
__device__ __forceinline__ void gemm_core_p(
    const ushort_t* __restrict__ A, int lda,
    const ushort_t* __restrict__ B, int ldb,
    int K, int tile_m, int tile_n,
    ushort_t* buf,                    // NS * (BM+BN)*32 ushorts
    floatx4 (&acc)[IM][IN]) {

    constexpr int NT = NW * 64;
    constexpr int SA = BM * 4 / NT;
    constexpr int SB = BN * 4 / NT;
    constexpr int Q  = SA + SB;
    constexpr int SLOT = (BM + BN) * 32;
    constexpr int BOFF = BM * 32;

    const int tid  = threadIdx.x;
    const int lane = tid & 63;
    const int wave = tid >> 6;
    const int wm   = wave >> 1, wn = wave & 1;
    const int quad = lane >> 4;
    const int l16  = lane & 15;

#pragma unroll
    for (int i = 0; i < IM; i++)
#pragma unroll
        for (int j = 0; j < IN; j++) acc[i][j] = (floatx4){0.f, 0.f, 0.f, 0.f};

    const ushort_t* ga[SA];
    int la[SA];
#pragma unroll
    for (int s = 0; s < SA; s++) {
        int seg = tid + s * NT;
        int r = seg >> 2, c = (seg ^ r ^ (r >> 2)) & 3;
        ga[s] = A + (long)(r + tile_m) * lda + c * 8;
        la[s] = seg * 8;
    }
    const ushort_t* gb[SB];
    int lb[SB];
#pragma unroll
    for (int s = 0; s < SB; s++) {
        int seg = tid + s * NT;
        int r = seg >> 2, c = (seg ^ r ^ (r >> 2)) & 3;
        gb[s] = B + (long)(r + tile_n) * ldb + c * 8;
        lb[s] = BOFF + seg * 8;
    }

    const int nk = K >> 5;

#pragma unroll
    for (int p = 0; p < NS - 1; ++p) {
#pragma unroll
        for (int s = 0; s < SA; s++) async16(ga[s] + p * 32, buf + p * SLOT + la[s]);
#pragma unroll
        for (int s = 0; s < SB; s++) async16(gb[s] + p * 32, buf + p * SLOT + lb[s]);
    }

    int slot = 0, slot2 = NS - 1;
    for (int k = 0; k < nk; ++k) {
        const int rem = nk - 1 - k;
        if (rem >= NS - 2) {
            vwait<(NS - 2) * Q>();
        } else if (NS >= 4 && rem == 1) {
            vwait<Q>();
        } else {
            vwait<0>();
        }
        __builtin_amdgcn_s_barrier();
        asm volatile("" ::: "memory");

        if (k + NS - 1 < nk) {
            const int koff = (k + NS - 1) << 5;
            ushort_t* dst = buf + slot2 * SLOT;
#pragma unroll
            for (int s = 0; s < SA; s++) async16(ga[s] + koff, dst + la[s]);
#pragma unroll
            for (int s = 0; s < SB; s++) async16(gb[s] + koff, dst + lb[s]);
        }

        const ushort_t* as = buf + slot * SLOT;
        const ushort_t* bs = as + BOFF;
        bf16x8 af[IM], bfr[IN];
#pragma unroll
        for (int im = 0; im < IM; im++)
            af[im] = *(const bf16x8*)&as[sw(wm * IM * 16 + im * 16 + l16, quad)];
#pragma unroll
        for (int in = 0; in < IN; in++)
            bfr[in] = *(const bf16x8*)&bs[sw(wn * IN * 16 + in * 16 + l16, quad)];
#pragma unroll
        for (int im = 0; im < IM; im++)
#pragma unroll
            for (int in = 0; in < IN; in++)
                acc[im][in] = __builtin_amdgcn_mfma_f32_16x16x32_bf16(
                    af[im], bfr[in], acc[im][in], 0, 0, 0);

        slot  = (slot == NS - 1) ? 0 : slot + 1;
        slot2 = (slot2 == NS - 1) ? 0 : slot2 + 1;
    }
}

// ---------------------------------------------------------------------------
// 256x256 / BK=64 / 8-wave 8-phase core, v3: template-faithful scheduling.
// NO sched_barrier, NO memory clobbers — bare waitcnt asm + raw s_barrier,
// exactly like the verified 8-phase exemplar; compiler does the fine
// lgkmcnt(N)-interleaved ds_read/MFMA scheduling. Steady loop body is
// branch-free; last two K-tiles peeled via MODE template.
//   MODE 0: steady (stage t+1.A1 / t+2.B0 / t+2.B1+A0 ; vmcnt(6))
//   MODE 1: penultimate (stage t+1.A1 only ; vmcnt(0))
//   MODE 2: last (no stage ; no vmcnt)
// Region hazard schedule identical to r2/r3 (verified correct).
// ---------------------------------------------------------------------------
template <int MODE>
__device__ __forceinline__ void tile256_body(
    const ushort_t* __restrict__ sb,    // read base, parity p (block-common)
    ushort_t* __restrict__ ldn,         // per-thread stage dest, parity pn
    ushort_t* __restrict__ ldc,         // per-thread stage dest, parity p
    const ushort_t* __restrict__ gA, const ushort_t* __restrict__ gB,
    int lda, int ldb, int t,
    int rb0, int rb1, int abase, int bbase,
    floatx4 (&acc)[8][4]) {

    bf16x8 aR[4][2], bKc[2][2], bCc[2][2];

    // ---------------- phase 1: quadrant (0,0) ----------------
#pragma unroll
    for (int fr = 0; fr < 4; fr++) {
        aR[fr][0] = *(const bf16x8*)&sb[abase + fr * 1024 + rb0];
        aR[fr][1] = *(const bf16x8*)&sb[abase + fr * 1024 + rb1];
    }
#pragma unroll
    for (int fc = 0; fc < 2; fc++) {
        bKc[fc][0] = *(const bf16x8*)&sb[bbase + fc * 1024 + rb0];
        bKc[fc][1] = *(const bf16x8*)&sb[bbase + fc * 1024 + rb1];
    }
    if constexpr (MODE <= 1) {   // stage (t+1).A1
        async16(gA + (long)128 * lda + (long)(t + 1) * 64, ldn + 8192);
        async16(gA + (long)192 * lda + (long)(t + 1) * 64, ldn + 12288);
    }
    asm volatile("s_waitcnt lgkmcnt(8)");
    __builtin_amdgcn_s_barrier();
    asm volatile("s_waitcnt lgkmcnt(0)");
    __builtin_amdgcn_s_setprio(1);
#pragma unroll
    for (int fr = 0; fr < 4; fr++)
#pragma unroll
        for (int fc = 0; fc < 2; fc++) {
            acc[fr][fc] = __builtin_amdgcn_mfma_f32_16x16x32_bf16(
                aR[fr][0], bKc[fc][0], acc[fr][fc], 0, 0, 0);
            acc[fr][fc] = __builtin_amdgcn_mfma_f32_16x16x32_bf16(
                aR[fr][1], bKc[fc][1], acc[fr][fc], 0, 0, 0);
        }
    __builtin_amdgcn_s_setprio(0);
    __builtin_amdgcn_s_barrier();

    // ---------------- phase 2: quadrant (0,1) ----------------
#pragma unroll
    for (int fc = 0; fc < 2; fc++) {
        bCc[fc][0] = *(const bf16x8*)&sb[bbase + (fc + 2) * 1024 + rb0];
        bCc[fc][1] = *(const bf16x8*)&sb[bbase + (fc + 2) * 1024 + rb1];
    }
    __builtin_amdgcn_s_barrier();
    asm volatile("s_waitcnt lgkmcnt(0)");
    __builtin_amdgcn_s_setprio(1);
#pragma unroll
    for (int fr = 0; fr < 4; fr++)
#pragma unroll
        for (int fc = 0; fc < 2; fc++) {
            acc[fr][fc + 2] = __builtin_amdgcn_mfma_f32_16x16x32_bf16(
                aR[fr][0], bCc[fc][0], acc[fr][fc + 2], 0, 0, 0);
            acc[fr][fc + 2] = __builtin_amdgcn_mfma_f32_16x16x32_bf16(
                aR[fr][1], bCc[fc][1], acc[fr][fc + 2], 0, 0, 0);
        }
    __builtin_amdgcn_s_setprio(0);
    __builtin_amdgcn_s_barrier();

    // ---------------- phase 3: quadrant (1,1) ----------------
#pragma unroll
    for (int fr = 0; fr < 4; fr++) {
        aR[fr][0] = *(const bf16x8*)&sb[abase + (fr + 4) * 1024 + rb0];
        aR[fr][1] = *(const bf16x8*)&sb[abase + (fr + 4) * 1024 + rb1];
    }
    if constexpr (MODE == 0) {   // stage (t+2).B0
        async16(gB + (long)(t + 2) * 64,                  ldc + 16384);
        async16(gB + (long)64 * ldb + (long)(t + 2) * 64, ldc + 20480);
    }
    __builtin_amdgcn_s_barrier();
    asm volatile("s_waitcnt lgkmcnt(0)");
    __builtin_amdgcn_s_setprio(1);
#pragma unroll
    for (int fr = 0; fr < 4; fr++)
#pragma unroll
        for (int fc = 0; fc < 2; fc++) {
            acc[fr + 4][fc + 2] = __builtin_amdgcn_mfma_f32_16x16x32_bf16(
                aR[fr][0], bCc[fc][0], acc[fr + 4][fc + 2], 0, 0, 0);
            acc[fr + 4][fc + 2] = __builtin_amdgcn_mfma_f32_16x16x32_bf16(
                aR[fr][1], bCc[fc][1], acc[fr + 4][fc + 2], 0, 0, 0);
        }
    __builtin_amdgcn_s_setprio(0);
    __builtin_amdgcn_s_barrier();

    // ---------------- phase 4: quadrant (1,0) ----------------
    if constexpr (MODE == 0) {   // stage (t+2).B1 + (t+2).A0
        async16(gB + (long)128 * ldb + (long)(t + 2) * 64, ldc + 24576);
        async16(gB + (long)192 * ldb + (long)(t + 2) * 64, ldc + 28672);
        async16(gA + (long)(t + 2) * 64,                   ldc);
        async16(gA + (long)64 * lda + (long)(t + 2) * 64,  ldc + 4096);
    }
    __builtin_amdgcn_s_barrier();
    __builtin_amdgcn_s_setprio(1);
#pragma unroll
    for (int fr = 0; fr < 4; fr++)
#pragma unroll
        for (int fc = 0; fc < 2; fc++) {
            acc[fr + 4][fc] = __builtin_amdgcn_mfma_f32_16x16x32_bf16(
                aR[fr][0], bKc[fc][0], acc[fr + 4][fc], 0, 0, 0);
            acc[fr + 4][fc] = __builtin_amdgcn_mfma_f32_16x16x32_bf16(
                aR[fr][1], bKc[fc][1], acc[fr + 4][fc], 0, 0, 0);
        }
    __builtin_amdgcn_s_setprio(0);
    if constexpr (MODE == 0) asm volatile("s_waitcnt vmcnt(6)");
    else if constexpr (MODE == 1) asm volatile("s_waitcnt vmcnt(0)");
    __builtin_amdgcn_s_barrier();
}

__device__ __forceinline__ void gemm256_8ph(
    const ushort_t* __restrict__ A, int lda,
    const ushort_t* __restrict__ B, int ldb,
    int K, int tile_m, int tile_n,
    ushort_t* buf,                      // 65536 ushorts = 128 KB
    floatx4 (&acc)[8][4]) {

    const int tid  = threadIdx.x;
    const int lane = tid & 63;
    const int wave = tid >> 6;
    const int wm   = wave >> 2;
    const int wn   = wave & 3;
    const int quad = lane >> 4;
    const int l16  = lane & 15;

#pragma unroll
    for (int i = 0; i < 8; i++)
#pragma unroll
        for (int j = 0; j < 4; j++) acc[i][j] = (floatx4){0.f, 0.f, 0.f, 0.f};

    const int srow = tid >> 3;                     // 0..63
    const int scg  = (tid & 7) ^ (srow & 7);
    const ushort_t* gA = A + (long)(tile_m + srow) * lda + scg * 8;
    const ushort_t* gB = B + (long)(tile_n + srow) * ldb + scg * 8;
    ushort_t* const ld = buf + tid * 8;

    const int rb0 = l16 * 64 + (((quad)     ^ (l16 & 7)) << 3);
    const int rb1 = l16 * 64 + (((quad + 4) ^ (l16 & 7)) << 3);
    const int abase = wm * 8192;
    const int bbase = 16384 + (wn >> 1) * 8192 + (wn & 1) * 4096;

    const int nt = K >> 6;

    // prologue: t0 {A0,B0,B1,A1}, t1 {B0,B1,A0}
    async16(gA,                    ld);            // t0.A0
    async16(gA + (long)64 * lda,   ld + 4096);
    async16(gB,                    ld + 16384);    // t0.B0
    async16(gB + (long)64 * ldb,   ld + 20480);
    async16(gB + (long)128 * ldb,  ld + 24576);    // t0.B1
    async16(gB + (long)192 * ldb,  ld + 28672);
    async16(gA + (long)128 * lda,  ld + 8192);     // t0.A1
    async16(gA + (long)192 * lda,  ld + 12288);
    async16(gB + 64,                   ld + 32768 + 16384);  // t1.B0
    async16(gB + (long)64 * ldb + 64,  ld + 32768 + 20480);
    async16(gB + (long)128 * ldb + 64, ld + 32768 + 24576);  // t1.B1
    async16(gB + (long)192 * ldb + 64, ld + 32768 + 28672);
    async16(gA + 64,                   ld + 32768);          // t1.A0
    async16(gA + (long)64 * lda + 64,  ld + 32768 + 4096);
    asm volatile("s_waitcnt vmcnt(6)");
    __builtin_amdgcn_s_barrier();

    int t = 0;
#pragma unroll 1
    for (; t < nt - 2; ++t) {
        const int p = t & 1;
        tile256_body<0>(buf + p * 32768, ld + (p ^ 1) * 32768, ld + p * 32768,
                        gA, gB, lda, ldb, t, rb0, rb1, abase, bbase, acc);
    }
    {
        const int p = t & 1;
        tile256_body<1>(buf + p * 32768, ld + (p ^ 1) * 32768, ld + p * 32768,
                        gA, gB, lda, ldb, t, rb0, rb1, abase, bbase, acc);
        ++t;
    }
    {
        const int p = t & 1;
        tile256_body<2>(buf + p * 32768, ld + (p ^ 1) * 32768, ld + p * 32768,
                        gA, gB, lda, ldb, t, rb0, rb1, abase, bbase, acc);
    }
}

// ---------------------------------------------------------------------------
// 128x256 / BK=64 / 8-wave counted-vmcnt 2-phase core, v3: template-faithful
// (no fences, branch-free steady body, MODE-peeled tail). Geometry/hazards
// identical to r3 (verified correct).
//   MODE 0: steady   (ph1 stage t+1.B1, vmcnt6 ; ph2 stage t+2.A+B0, vmcnt6)
//   MODE 1: penult   (ph1 stage t+1.B1, vmcnt6 ; ph2 no stage, vmcnt2)
//   MODE 2: last     (ph1 no stage, vmcnt0     ; ph2 no stage, no vmcnt)
// ---------------------------------------------------------------------------
template <int MODE>
__device__ __forceinline__ void tile_bn256_body(
    const ushort_t* __restrict__ sb,    // read base, parity p
    ushort_t* __restrict__ ldn,         // per-thread stage dest, parity pn
    ushort_t* __restrict__ ldc,         // per-thread stage dest, parity p
    const ushort_t* __restrict__ gA, const ushort_t* __restrict__ gB,
    int lda, int ldb, int t,
    int rb0, int rb1, int ab, int bb,
    floatx4 (&acc)[4][4]) {

    bf16x8 aR[4][2], bKc[2][2], bCc[2][2];

    // ---------------- phase 1: fc 0-1 (B unit B0) ----------------
#pragma unroll
    for (int fr = 0; fr < 4; fr++) {
        aR[fr][0] = *(const bf16x8*)&sb[ab + fr * 1024 + rb0];
        aR[fr][1] = *(const bf16x8*)&sb[ab + fr * 1024 + rb1];
    }
#pragma unroll
    for (int fc = 0; fc < 2; fc++) {
        bKc[fc][0] = *(const bf16x8*)&sb[bb + fc * 4096 + rb0];
        bKc[fc][1] = *(const bf16x8*)&sb[bb + fc * 4096 + rb1];
    }
    if constexpr (MODE <= 1) {   // stage (t+1).B1
        async16(gB + (long)128 * ldb + (long)(t + 1) * 64, ldn + 16384);
        async16(gB + (long)192 * ldb + (long)(t + 1) * 64, ldn + 20480);
    }
    asm volatile("s_waitcnt lgkmcnt(8)");
    __builtin_amdgcn_s_barrier();
    asm volatile("s_waitcnt lgkmcnt(0)");
    __builtin_amdgcn_s_setprio(1);
#pragma unroll
    for (int fr = 0; fr < 4; fr++)
#pragma unroll
        for (int fc = 0; fc < 2; fc++) {
            acc[fr][fc] = __builtin_amdgcn_mfma_f32_16x16x32_bf16(
                aR[fr][0], bKc[fc][0], acc[fr][fc], 0, 0, 0);
            acc[fr][fc] = __builtin_amdgcn_mfma_f32_16x16x32_bf16(
                aR[fr][1], bKc[fc][1], acc[fr][fc], 0, 0, 0);
        }
    __builtin_amdgcn_s_setprio(0);
    if constexpr (MODE <= 1) asm volatile("s_waitcnt vmcnt(6)");
    else                     asm volatile("s_waitcnt vmcnt(0)");
    __builtin_amdgcn_s_barrier();

    // ---------------- phase 2: fc 2-3 (B unit B1) ----------------
#pragma unroll
    for (int fc = 0; fc < 2; fc++) {
        bCc[fc][0] = *(const bf16x8*)&sb[bb + (fc + 2) * 4096 + rb0];
        bCc[fc][1] = *(const bf16x8*)&sb[bb + (fc + 2) * 4096 + rb1];
    }
    if constexpr (MODE == 0) {   // stage (t+2).A + (t+2).B0
        async16(gA + (long)(t + 2) * 64,                  ldc);
        async16(gA + (long)64 * lda + (long)(t + 2) * 64, ldc + 4096);
        async16(gB + (long)(t + 2) * 64,                  ldc + 8192);
        async16(gB + (long)64 * ldb + (long)(t + 2) * 64, ldc + 12288);
    }
    __builtin_amdgcn_s_barrier();
    asm volatile("s_waitcnt lgkmcnt(0)");
    __builtin_amdgcn_s_setprio(1);
#pragma unroll
    for (int fr = 0; fr < 4; fr++)
#pragma unroll
        for (int fc = 0; fc < 2; fc++) {
            acc[fr][fc + 2] = __builtin_amdgcn_mfma_f32_16x16x32_bf16(
                aR[fr][0], bCc[fc][0], acc[fr][fc + 2], 0, 0, 0);
            acc[fr][fc + 2] = __builtin_amdgcn_mfma_f32_16x16x32_bf16(
                aR[fr][1], bCc[fc][1], acc[fr][fc + 2], 0, 0, 0);
        }
    __builtin_amdgcn_s_setprio(0);
    if constexpr (MODE == 0)      asm volatile("s_waitcnt vmcnt(6)");
    else if constexpr (MODE == 1) asm volatile("s_waitcnt vmcnt(2)");
    __builtin_amdgcn_s_barrier();
}

__device__ __forceinline__ void gemm_bn256_2ph(
    const ushort_t* __restrict__ A, int lda,
    const ushort_t* __restrict__ B, int ldb,
    int K, int tile_m, int tile_n,
    ushort_t* buf,                      // 49152 ushorts = 96 KB
    floatx4 (&acc)[4][4]) {

    const int tid  = threadIdx.x;
    const int lane = tid & 63;
    const int wave = tid >> 6;
    const int wm   = wave >> 2;
    const int wn   = wave & 3;
    const int quad = lane >> 4;
    const int l16  = lane & 15;

#pragma unroll
    for (int i = 0; i < 4; i++)
#pragma unroll
        for (int j = 0; j < 4; j++) acc[i][j] = (floatx4){0.f, 0.f, 0.f, 0.f};

    const int srow = tid >> 3;
    const int scg  = (tid & 7) ^ (srow & 7);
    const ushort_t* gA = A + (long)(tile_m + srow) * lda + scg * 8;
    const ushort_t* gB = B + (long)(tile_n + srow) * ldb + scg * 8;
    ushort_t* const ld = buf + tid * 8;

    const int rb0 = l16 * 64 + (((quad)     ^ (l16 & 7)) << 3);
    const int rb1 = l16 * 64 + (((quad + 4) ^ (l16 & 7)) << 3);
    const int ab = wm * 4096;                 // A row = wm*64 + fr*16 + l16
    const int bb = 8192 + wn * 1024;          // B row = fc*64 + wn*16 + l16

    const int nt = K >> 6;

    // prologue: t0 {A,B0,B1}, t1 {A,B0}
    async16(gA,                    ld);
    async16(gA + (long)64 * lda,   ld + 4096);
    async16(gB,                    ld + 8192);
    async16(gB + (long)64 * ldb,   ld + 12288);
    async16(gB + (long)128 * ldb,  ld + 16384);
    async16(gB + (long)192 * ldb,  ld + 20480);
    async16(gA + 64,                   ld + 24576);
    async16(gA + (long)64 * lda + 64,  ld + 24576 + 4096);
    async16(gB + 64,                   ld + 24576 + 8192);
    async16(gB + (long)64 * ldb + 64,  ld + 24576 + 12288);
    asm volatile("s_waitcnt vmcnt(4)");
    __builtin_amdgcn_s_barrier();

    int t = 0;
#pragma unroll 1
    for (; t < nt - 2; ++t) {
        const int p = t & 1;
        tile_bn256_body<0>(buf + p * 24576, ld + (p ^ 1) * 24576, ld + p * 24576,
                           gA, gB, lda, ldb, t, rb0, rb1, ab, bb, acc);
    }
    {
        const int p = t & 1;
        tile_bn256_body<1>(buf + p * 24576, ld + (p ^ 1) * 24576, ld + p * 24576,
                           gA, gB, lda, ldb, t, rb0, rb1, ab, bb, acc);
        ++t;
    }
    {
        const int p = t & 1;
        tile_bn256_body<2>(buf + p * 24576, ld + (p ^ 1) * 24576, ld + p * 24576,
                           gA, gB, lda, ldb, t, rb0, rb1, ab, bb, acc);
    }
}

// ---------------------------------------------------------------------------
// prep: fp32->bf16 for x & W_v, zero lsum, transpose+cast Wq/Wk -> WqT/WkT
// ---------------------------------------------------------------------------
__global__ void prep_kernel(const float* __restrict__ x,
                            const float* __restrict__ wq,
                            const float* __restrict__ wk,
                            const float* __restrict__ wv,
                            ushort_t* __restrict__ xb,
                            ushort_t* __restrict__ wvb,
                            ushort_t* __restrict__ wqT,
                            ushort_t* __restrict__ wkT,
                            float* __restrict__ lsum) {
    const int bx = blockIdx.x;
    const int t = threadIdx.x;
    if (bx < 9216) {
        const float* src;
        ushort_t* dst;
        long g;
        if (bx < 8192) { src = x;  dst = xb;  g = ((long)bx * 256 + t) * 4; }
        else           { src = wv; dst = wvb; g = ((long)(bx - 8192) * 256 + t) * 4; }
        float4 v = *(const float4*)(src + g);
        ushort4 o;
        o.x = f2bf(v.x); o.y = f2bf(v.y); o.z = f2bf(v.z); o.w = f2bf(v.w);
        *(ushort4*)(dst + g) = o;
        return;
    }
    if (bx < 9224) {
        int idx = (bx - 9216) * 256 + t;  // [0,2048)
        ((float4*)lsum)[idx] = (float4){0.f, 0.f, 0.f, 0.f};
        return;
    }
    const int tt = bx - 9224;           // [0,512)
    const float* src = (tt >= 256) ? wk : wq;
    ushort_t* dst = (tt >= 256) ? wkT : wqT;
    const int id = tt & 255;
    const int h0 = (id >> 4) * 64, d0 = (id & 15) * 64;
    __shared__ ushort_t tile[64 * 80];
    {
        int i = t >> 2, cg = (t & 3) << 4;
        const float4* p = (const float4*)(src + (long)(h0 + i) * 1024 + d0 + cg);
#pragma unroll
        for (int k = 0; k < 4; k++) {
            float4 v = p[k];
            ushort_t* q = &tile[i * 80 + cg + k * 4];
            q[0] = f2bf(v.x); q[1] = f2bf(v.y); q[2] = f2bf(v.z); q[3] = f2bf(v.w);
        }
    }
    __syncthreads();
    {
        int j = t >> 2, ig = (t & 3) << 4;
        ushort_t tmp[16];
#pragma unroll
        for (int k = 0; k < 16; k++) tmp[k] = tile[(ig + k) * 80 + j];
        ushort_t* o = dst + (long)(d0 + j) * 1024 + h0 + ig;
        *(uint4*)o = ((uint4*)tmp)[0];
        *(uint4*)(o + 8) = ((uint4*)tmp)[1];
    }
}

// ---------------------------------------------------------------------------
// gv: blocks [0,32) -> G ; [32,288) -> V^T.  (legacy core, NS=3)
// ---------------------------------------------------------------------------
__global__ __launch_bounds__(512, 4) void gv_kernel(
    const ushort_t* __restrict__ wkT, const ushort_t* __restrict__ wqT,
    const ushort_t* __restrict__ wvb, const ushort_t* __restrict__ xb,
    ushort_t* __restrict__ Gb, ushort_t* __restrict__ VTb) {

    __shared__ __align__(16) ushort_t buf[3 * 384 * 32];

    const ushort_t *A, *B;
    ushort_t* C;
    int ldc, tile_m, tile_n;
    if (blockIdx.x < 32) {
        A = wkT; B = wqT; C = Gb; ldc = 1024;
        tile_m = (blockIdx.x >> 3) * 256;
        tile_n = (blockIdx.x & 7) * 128;
    } else {
        int id = blockIdx.x - 32;
        A = wvb; B = xb; C = VTb; ldc = 8192;
        tile_m = (id >> 6) * 256;
        tile_n = (id & 63) * 128;
    }

    floatx4 acc[4][4];
    gemm_core_p<256, 128, 4, 4, 8, 3>(A, 1024, B, 1024, 1024, tile_m, tile_n, buf, acc);

    const int lane = threadIdx.x & 63, wave = threadIdx.x >> 6;
    const int wm = wave >> 1, wn = wave & 1, quad = lane >> 4, l16 = lane & 15;
#pragma unroll
    for (int im = 0; im < 4; im++)
#pragma unroll
        for (int r = 0; r < 4; r++) {
            int row = tile_m + wm * 64 + im * 16 + quad * 4 + r;
#pragma unroll
            for (int in = 0; in < 4; in++) {
                int col = tile_n + wn * 64 + in * 16 + l16;
                C[(long)row * ldc + col] = f2bf(acc[im][in][r]);
            }
        }
}

// ---------------------------------------------------------------------------
// Y = x G^T  (M=8192, N=1024, K=1024; 128x256 tiles, 256 blocks = 1/CU)
// ---------------------------------------------------------------------------
__global__ __launch_bounds__(512, 2) void y_kernel(
    const ushort_t* __restrict__ xb,
    const ushort_t* __restrict__ Gb,
    ushort_t* __restrict__ Yb) {

    __shared__ __align__(16) ushort_t buf[49152];   // 96 KB
    const int lin = xcd_swz(blockIdx.x, 32);        // 256 blocks
    const int tile_m = (lin >> 2) * 128;            // 64 m-tiles
    const int tile_n = (lin & 3) * 256;             // 4 n-tiles (fastest)

    floatx4 acc[4][4];
    gemm_bn256_2ph(xb, 1024, Gb, 1024, 1024, tile_m, tile_n, buf, acc);

    const int lane = threadIdx.x & 63, wave = threadIdx.x >> 6;
    const int wm = wave >> 2, wn = wave & 3, quad = lane >> 4, l16 = lane & 15;
#pragma unroll
    for (int fr = 0; fr < 4; fr++)
#pragma unroll
        for (int r = 0; r < 4; r++) {
            int row = tile_m + wm * 64 + fr * 16 + quad * 4 + r;
#pragma unroll
            for (int fc = 0; fc < 4; fc++) {
                int col = tile_n + fc * 64 + wn * 16 + l16;
                Yb[(long)row * 1024 + col] = f2bf(acc[fr][fc][r]);
            }
        }
}

// ---------------------------------------------------------------------------
// P = exp(scale * Y x^T) per batch + fused row-sum atomics.
// 256x256 8-phase v3 core, 256 blocks = 1/CU, 128 KB LDS, 8 waves.
// ---------------------------------------------------------------------------
__global__ __launch_bounds__(512, 2) void pexp_kernel(
    const ushort_t* __restrict__ Yb,
    const ushort_t* __restrict__ xb,
    ushort_t* __restrict__ Pb,
    float* __restrict__ lsum) {

    __shared__ __align__(16) ushort_t buf[65536];   // 128 KB

    const int lin = xcd_swz(blockIdx.x, 32);   // 256 blocks, bijective
    const int z = lin >> 6;                    // batch
    const int tile_m = ((lin >> 3) & 7) * 256; // 8 m-tiles
    const int tile_n = (lin & 7) * 256;        // 8 n-tiles

    const ushort_t* A = Yb + (long)z * 2097152;
    const ushort_t* B = xb + (long)z * 2097152;
    ushort_t* C = Pb + (long)z * 4194304;
    float* l = lsum + z * 2048;

    floatx4 acc[8][4];
    gemm256_8ph(A, 1024, B, 1024, 1024, tile_m, tile_n, buf, acc);

    const float scale = 0.022097086912079608f;  // 1/sqrt(2048)
    const int lane = threadIdx.x & 63, wave = threadIdx.x >> 6;
    const int wm = wave >> 2, wn = wave & 3, quad = lane >> 4, l16 = lane & 15;
#pragma unroll
    for (int fr = 0; fr < 8; fr++)
#pragma unroll
        for (int rr = 0; rr < 4; rr++) {
            int row = tile_m + wm * 128 + fr * 16 + quad * 4 + rr;
            float psum = 0.f;
#pragma unroll
            for (int fc = 0; fc < 4; fc++) {
                int col = tile_n + wn * 64 + fc * 16 + l16;
                float e = __expf(acc[fr][fc][rr] * scale);
                C[(long)row * 2048 + col] = f2bf(e);
                psum += e;
            }
            psum += __shfl_xor(psum, 1, 64);
            psum += __shfl_xor(psum, 2, 64);
            psum += __shfl_xor(psum, 4, 64);
            psum += __shfl_xor(psum, 8, 64);
            if (l16 == 0) atomicAdd(&l[row], psum);
        }
}

// ---------------------------------------------------------------------------
// out = (P V) / l per batch  (128x256 tiles, K=2048, 256 blocks = 1/CU)
// ---------------------------------------------------------------------------
__global__ __launch_bounds__(512, 2) void out_kernel(
    const ushort_t* __restrict__ Pb,
    const ushort_t* __restrict__ VTb,
    float* __restrict__ out,
    const float* __restrict__ lsum) {

    __shared__ __align__(16) ushort_t buf[49152];   // 96 KB

    const int lin = xcd_swz(blockIdx.x, 32);   // 256 blocks
    const int z = lin >> 6;                    // batch
    const int tile_m = ((lin >> 2) & 15) * 128;// 16 m-tiles
    const int tile_n = (lin & 3) * 256;        // 4 n-tiles (fastest)

    const ushort_t* A = Pb + (long)z * 4194304;   // [2048][2048]
    const ushort_t* B = VTb + (long)z * 2048;     // ldb=8192, batch col slice
    float* C = out + (long)z * 2097152;
    const float* l = lsum + z * 2048;

    floatx4 acc[4][4];
    gemm_bn256_2ph(A, 2048, B, 8192, 2048, tile_m, tile_n, buf, acc);

    const int lane = threadIdx.x & 63, wave = threadIdx.x >> 6;
    const int wm = wave >> 2, wn = wave & 3, quad = lane >> 4, l16 = lane & 15;
#pragma unroll
    for (int fr = 0; fr < 4; fr++)
#pragma unroll
        for (int r = 0; r < 4; r++) {
            int row = tile_m + wm * 64 + fr * 16 + quad * 4 + r;
            float li = 1.0f / l[row];
#pragma unroll
            for (int fc = 0; fc < 4; fc++) {
                int col = tile_n + fc * 64 + wn * 16 + l16;
                C[(long)row * 1024 + col] = acc[fr][fc][r] * li;
            }
        }
}

// ---------------------------------------------------------------------------
extern "C" void kernel_launch(void* const* d_in, const int* in_sizes, int n_in,
                              void* d_out, int out_size, void* d_ws, size_t ws_size,
                              hipStream_t stream) {
    const float* x  = (const float*)d_in[0];
    const float* wq = (const float*)d_in[1];
    const float* wk = (const float*)d_in[2];
    const float* wv = (const float*)d_in[3];

    ushort_t* xb  = (ushort_t*)d_ws;          // [8192,1024] bf16
    ushort_t* wvb = xb  + 8388608;            // [1024,1024]
    ushort_t* wqT = wvb + 1048576;            // [1024,1024]
    ushort_t* wkT = wqT + 1048576;            // [1024,1024]
    ushort_t* Gb  = wkT + 1048576;            // [1024,1024]
    ushort_t* Yb  = Gb  + 1048576;            // [8192,1024]
    ushort_t* VTb = Yb  + 8388608;            // [1024,8192]
    ushort_t* Pb  = VTb + 8388608;            // [4][2048][2048]
    float*    lsum = (float*)(Pb + 16777216); // [4][2048]
    float*    out  = (float*)d_out;

    prep_kernel<<<9736, 256, 0, stream>>>(x, wq, wk, wv, xb, wvb, wqT, wkT, lsum);
    gv_kernel<<<288, 512, 0, stream>>>(wkT, wqT, wvb, xb, Gb, VTb);
    y_kernel<<<256, 512, 0, stream>>>(xb, Gb, Yb);
    pexp_kernel<<<256, 512, 0, stream>>>(Yb, xb, Pb, lsum);
    out_kernel<<<256, 512, 0, stream>>>(Pb, VTb, out, lsum);
}

// Round 5
// 219.256 us; speedup vs baseline: 1.0533x; 1.0451x over previous
//
#include <hip/hip_runtime.h>

typedef unsigned short ushort_t;
typedef __attribute__((ext_vector_type(8))) __bf16 bf16x8;
typedef __attribute__((ext_vector_type(4))) float floatx4;

__device__ __forceinline__ ushort_t f2bf(float f) {
    unsigned int u = __builtin_bit_cast(unsigned int, f);
    u = (u + 0x7fffu + ((u >> 16) & 1u)) >> 16;
    return (ushort_t)u;
}

__device__ __forceinline__ void async16(const ushort_t* g, ushort_t* l) {
    __builtin_amdgcn_global_load_lds(
        (const __attribute__((address_space(1))) unsigned int*)g,
        (__attribute__((address_space(3))) unsigned int*)l,
        16 /*bytes*/, 0 /*offset*/, 0 /*aux*/);
}

// XCD-chunked bijective blockIdx swizzle (nwg % 8 == 0).
__device__ __forceinline__ int xcd_swz(int bid, int cpx) {
    return (bid & 7) * cpx + (bid >> 3);
}

// ===========================================================================
// FREE-RUN cores: ONE vmcnt + ONE s_barrier per K-tile; no intra-tile
// barriers. Safe because every DMA stage targets a buffer region that is
// never read in the current or adjacent tile:
//   t3 (triple-buffer): stage(t+2) -> buf[(t+2)%3]; last read in tile t-1,
//       all waves passed barrier-t after those reads -> disjoint.  vmcnt(6).
//   d2 (double-buffer): stage(t+1) -> parity pn; last read in tile t-1,
//       all waves passed barrier-t -> disjoint.  vmcnt(0) (issued 1 tile ago).
// Within a tile, waves free-run through quadrants (compiler inserts its own
// lgkmcnt for ds_read->MFMA deps); wave skew overlaps LDS reads with MFMA.
// Read swizzle (16B-slot = (kk*4+quad)^(row&7)) + pre-swizzled global source
// identical to the verified r2-r4 layout; epilogue mappings unchanged.
// ===========================================================================

// ---------------------------------------------------------------------------
// fr_bn256: 128x256 / BK=64 / 8-wave / triple-buffer (144 KB).
// Buffer layout (ushorts, SL=24576): A[128][64] @0 ; B[256][64] @8192.
// Wave (wm 0..1)x(wn 0..3), per-wave C = 64x64 = acc[4][4]; B fc-major.
// ---------------------------------------------------------------------------
template <int MODE>   // 0 steady (stage t+2, vmcnt6) | 1 penult (vmcnt6) | 2 last (vmcnt0)
__device__ __forceinline__ void frbn_tile(
    const ushort_t* __restrict__ sb, ushort_t* __restrict__ dst,
    const ushort_t* __restrict__ gA, const ushort_t* __restrict__ gB,
    int lda, int ldb, long koff,
    int rb0, int rb1, int ab, int bb,
    floatx4 (&acc)[4][4]) {

    if constexpr (MODE == 2) asm volatile("s_waitcnt vmcnt(0)");
    else                     asm volatile("s_waitcnt vmcnt(6)");
    __builtin_amdgcn_s_barrier();

    if constexpr (MODE == 0) {
        async16(gA + koff,                   dst);
        async16(gA + (long)64 * lda + koff,  dst + 4096);
        async16(gB + koff,                   dst + 8192);
        async16(gB + (long)64 * ldb + koff,  dst + 12288);
        async16(gB + (long)128 * ldb + koff, dst + 16384);
        async16(gB + (long)192 * ldb + koff, dst + 20480);
    }

    bf16x8 aR[4][2], bKc[2][2], bCc[2][2];
    // phase 1: fc 0-1
#pragma unroll
    for (int fr = 0; fr < 4; fr++) {
        aR[fr][0] = *(const bf16x8*)&sb[ab + fr * 1024 + rb0];
        aR[fr][1] = *(const bf16x8*)&sb[ab + fr * 1024 + rb1];
    }
#pragma unroll
    for (int fc = 0; fc < 2; fc++) {
        bKc[fc][0] = *(const bf16x8*)&sb[bb + fc * 4096 + rb0];
        bKc[fc][1] = *(const bf16x8*)&sb[bb + fc * 4096 + rb1];
    }
    __builtin_amdgcn_s_setprio(1);
#pragma unroll
    for (int fr = 0; fr < 4; fr++)
#pragma unroll
        for (int fc = 0; fc < 2; fc++) {
            acc[fr][fc] = __builtin_amdgcn_mfma_f32_16x16x32_bf16(
                aR[fr][0], bKc[fc][0], acc[fr][fc], 0, 0, 0);
            acc[fr][fc] = __builtin_amdgcn_mfma_f32_16x16x32_bf16(
                aR[fr][1], bKc[fc][1], acc[fr][fc], 0, 0, 0);
        }
    __builtin_amdgcn_s_setprio(0);

    // phase 2: fc 2-3
#pragma unroll
    for (int fc = 0; fc < 2; fc++) {
        bCc[fc][0] = *(const bf16x8*)&sb[bb + (fc + 2) * 4096 + rb0];
        bCc[fc][1] = *(const bf16x8*)&sb[bb + (fc + 2) * 4096 + rb1];
    }
    __builtin_amdgcn_s_setprio(1);
#pragma unroll
    for (int fr = 0; fr < 4; fr++)
#pragma unroll
        for (int fc = 0; fc < 2; fc++) {
            acc[fr][fc + 2] = __builtin_amdgcn_mfma_f32_16x16x32_bf16(
                aR[fr][0], bCc[fc][0], acc[fr][fc + 2], 0, 0, 0);
            acc[fr][fc + 2] = __builtin_amdgcn_mfma_f32_16x16x32_bf16(
                aR[fr][1], bCc[fc][1], acc[fr][fc + 2], 0, 0, 0);
        }
    __builtin_amdgcn_s_setprio(0);
}

__device__ __forceinline__ void gemm_frbn(
    const ushort_t* __restrict__ A, int lda,
    const ushort_t* __restrict__ B, int ldb,
    int K, int tile_m, int tile_n,
    ushort_t* buf,                      // 73728 ushorts = 144 KB
    floatx4 (&acc)[4][4]) {

    const int tid  = threadIdx.x;
    const int lane = tid & 63;
    const int wave = tid >> 6;
    const int wm   = wave >> 2;
    const int wn   = wave & 3;
    const int quad = lane >> 4;
    const int l16  = lane & 15;

#pragma unroll
    for (int i = 0; i < 4; i++)
#pragma unroll
        for (int j = 0; j < 4; j++) acc[i][j] = (floatx4){0.f, 0.f, 0.f, 0.f};

    const int srow = tid >> 3;
    const int scg  = (tid & 7) ^ (srow & 7);
    const ushort_t* gA = A + (long)(tile_m + srow) * lda + scg * 8;
    const ushort_t* gB = B + (long)(tile_n + srow) * ldb + scg * 8;
    ushort_t* const ld = buf + tid * 8;

    const int rb0 = l16 * 64 + (((quad)     ^ (l16 & 7)) << 3);
    const int rb1 = l16 * 64 + (((quad + 4) ^ (l16 & 7)) << 3);
    const int ab = wm * 4096;                 // A row = wm*64 + fr*16 + l16
    const int bb = 8192 + wn * 1024;          // B row = fc*64 + wn*16 + l16

    const int nt = K >> 6;

    // prologue: t0 -> buf0, t1 -> buf1
    async16(gA,                        ld);
    async16(gA + (long)64 * lda,       ld + 4096);
    async16(gB,                        ld + 8192);
    async16(gB + (long)64 * ldb,       ld + 12288);
    async16(gB + (long)128 * ldb,      ld + 16384);
    async16(gB + (long)192 * ldb,      ld + 20480);
    async16(gA + 64,                   ld + 24576);
    async16(gA + (long)64 * lda + 64,  ld + 24576 + 4096);
    async16(gB + 64,                   ld + 24576 + 8192);
    async16(gB + (long)64 * ldb + 64,  ld + 24576 + 12288);
    async16(gB + (long)128 * ldb + 64, ld + 24576 + 16384);
    async16(gB + (long)192 * ldb + 64, ld + 24576 + 20480);

    int cur = 0;
    int t = 0;
#pragma unroll 1
    for (; t < nt - 2; ++t) {
        const int nx = (cur == 0) ? 2 : cur - 1;   // (cur+2)%3
        frbn_tile<0>(buf + cur * 24576, ld + nx * 24576,
                     gA, gB, lda, ldb, (long)(t + 2) * 64,
                     rb0, rb1, ab, bb, acc);
        cur = (cur == 2) ? 0 : cur + 1;
    }
    frbn_tile<1>(buf + cur * 24576, ld, gA, gB, lda, ldb, 0,
                 rb0, rb1, ab, bb, acc);
    cur = (cur == 2) ? 0 : cur + 1;
    frbn_tile<2>(buf + cur * 24576, ld, gA, gB, lda, ldb, 0,
                 rb0, rb1, ab, bb, acc);
}

// ---------------------------------------------------------------------------
// fr256: 256x256 / BK=64 / 8-wave / double-buffer free-run (128 KB).
// Buffer layout per parity (32768 u): A halves @0/@8192, B halves @16384/@24576.
// Wave (wm 0..1)x(wn 0..3), per-wave C = 128x64 = acc[8][4]; snake quadrants.
// ---------------------------------------------------------------------------
template <int MODE>   // 0 steady (stage t+1) | 1 last (no stage)
__device__ __forceinline__ void fr256_tile(
    const ushort_t* __restrict__ sb, ushort_t* __restrict__ dst,
    const ushort_t* __restrict__ gA, const ushort_t* __restrict__ gB,
    int lda, int ldb, long koff,
    int rb0, int rb1, int abase, int bbase,
    floatx4 (&acc)[8][4]) {

    asm volatile("s_waitcnt vmcnt(0)");
    __builtin_amdgcn_s_barrier();

    if constexpr (MODE == 0) {
        async16(gA + koff,                   dst);
        async16(gA + (long)64 * lda + koff,  dst + 4096);
        async16(gA + (long)128 * lda + koff, dst + 8192);
        async16(gA + (long)192 * lda + koff, dst + 12288);
        async16(gB + koff,                   dst + 16384);
        async16(gB + (long)64 * ldb + koff,  dst + 20480);
        async16(gB + (long)128 * ldb + koff, dst + 24576);
        async16(gB + (long)192 * ldb + koff, dst + 28672);
    }

    bf16x8 aR[4][2], bKc[2][2], bCc[2][2];

    // quadrant (0,0)
#pragma unroll
    for (int fr = 0; fr < 4; fr++) {
        aR[fr][0] = *(const bf16x8*)&sb[abase + fr * 1024 + rb0];
        aR[fr][1] = *(const bf16x8*)&sb[abase + fr * 1024 + rb1];
    }
#pragma unroll
    for (int fc = 0; fc < 2; fc++) {
        bKc[fc][0] = *(const bf16x8*)&sb[bbase + fc * 1024 + rb0];
        bKc[fc][1] = *(const bf16x8*)&sb[bbase + fc * 1024 + rb1];
    }
    __builtin_amdgcn_s_setprio(1);
#pragma unroll
    for (int fr = 0; fr < 4; fr++)
#pragma unroll
        for (int fc = 0; fc < 2; fc++) {
            acc[fr][fc] = __builtin_amdgcn_mfma_f32_16x16x32_bf16(
                aR[fr][0], bKc[fc][0], acc[fr][fc], 0, 0, 0);
            acc[fr][fc] = __builtin_amdgcn_mfma_f32_16x16x32_bf16(
                aR[fr][1], bKc[fc][1], acc[fr][fc], 0, 0, 0);
        }
    __builtin_amdgcn_s_setprio(0);

    // quadrant (0,1)
#pragma unroll
    for (int fc = 0; fc < 2; fc++) {
        bCc[fc][0] = *(const bf16x8*)&sb[bbase + (fc + 2) * 1024 + rb0];
        bCc[fc][1] = *(const bf16x8*)&sb[bbase + (fc + 2) * 1024 + rb1];
    }
    __builtin_amdgcn_s_setprio(1);
#pragma unroll
    for (int fr = 0; fr < 4; fr++)
#pragma unroll
        for (int fc = 0; fc < 2; fc++) {
            acc[fr][fc + 2] = __builtin_amdgcn_mfma_f32_16x16x32_bf16(
                aR[fr][0], bCc[fc][0], acc[fr][fc + 2], 0, 0, 0);
            acc[fr][fc + 2] = __builtin_amdgcn_mfma_f32_16x16x32_bf16(
                aR[fr][1], bCc[fc][1], acc[fr][fc + 2], 0, 0, 0);
        }
    __builtin_amdgcn_s_setprio(0);

    // quadrant (1,1)  (reuse aR regs for A fr4-7)
#pragma unroll
    for (int fr = 0; fr < 4; fr++) {
        aR[fr][0] = *(const bf16x8*)&sb[abase + (fr + 4) * 1024 + rb0];
        aR[fr][1] = *(const bf16x8*)&sb[abase + (fr + 4) * 1024 + rb1];
    }
    __builtin_amdgcn_s_setprio(1);
#pragma unroll
    for (int fr = 0; fr < 4; fr++)
#pragma unroll
        for (int fc = 0; fc < 2; fc++) {
            acc[fr + 4][fc + 2] = __builtin_amdgcn_mfma_f32_16x16x32_bf16(
                aR[fr][0], bCc[fc][0], acc[fr + 4][fc + 2], 0, 0, 0);
            acc[fr + 4][fc + 2] = __builtin_amdgcn_mfma_f32_16x16x32_bf16(
                aR[fr][1], bCc[fc][1], acc[fr + 4][fc + 2], 0, 0, 0);
        }
    __builtin_amdgcn_s_setprio(0);

    // quadrant (1,0)  (registers held)
    __builtin_amdgcn_s_setprio(1);
#pragma unroll
    for (int fr = 0; fr < 4; fr++)
#pragma unroll
        for (int fc = 0; fc < 2; fc++) {
            acc[fr + 4][fc] = __builtin_amdgcn_mfma_f32_16x16x32_bf16(
                aR[fr][0], bKc[fc][0], acc[fr + 4][fc], 0, 0, 0);
            acc[fr + 4][fc] = __builtin_amdgcn_mfma_f32_16x16x32_bf16(
                aR[fr][1], bKc[fc][1], acc[fr + 4][fc], 0, 0, 0);
        }
    __builtin_amdgcn_s_setprio(0);
}

__device__ __forceinline__ void gemm_fr256(
    const ushort_t* __restrict__ A, int lda,
    const ushort_t* __restrict__ B, int ldb,
    int K, int tile_m, int tile_n,
    ushort_t* buf,                      // 65536 ushorts = 128 KB
    floatx4 (&acc)[8][4]) {

    const int tid  = threadIdx.x;
    const int lane = tid & 63;
    const int wave = tid >> 6;
    const int wm   = wave >> 2;
    const int wn   = wave & 3;
    const int quad = lane >> 4;
    const int l16  = lane & 15;

#pragma unroll
    for (int i = 0; i < 8; i++)
#pragma unroll
        for (int j = 0; j < 4; j++) acc[i][j] = (floatx4){0.f, 0.f, 0.f, 0.f};

    const int srow = tid >> 3;
    const int scg  = (tid & 7) ^ (srow & 7);
    const ushort_t* gA = A + (long)(tile_m + srow) * lda + scg * 8;
    const ushort_t* gB = B + (long)(tile_n + srow) * ldb + scg * 8;
    ushort_t* const ld = buf + tid * 8;

    const int rb0 = l16 * 64 + (((quad)     ^ (l16 & 7)) << 3);
    const int rb1 = l16 * 64 + (((quad + 4) ^ (l16 & 7)) << 3);
    const int abase = wm * 8192;
    const int bbase = 16384 + (wn >> 1) * 8192 + (wn & 1) * 4096;

    const int nt = K >> 6;

    // prologue: stage t0 -> parity 0
    async16(gA,                   ld);
    async16(gA + (long)64 * lda,  ld + 4096);
    async16(gA + (long)128 * lda, ld + 8192);
    async16(gA + (long)192 * lda, ld + 12288);
    async16(gB,                   ld + 16384);
    async16(gB + (long)64 * ldb,  ld + 20480);
    async16(gB + (long)128 * ldb, ld + 24576);
    async16(gB + (long)192 * ldb, ld + 28672);

    int t = 0;
#pragma unroll 1
    for (; t < nt - 1; ++t) {
        const int p = t & 1;
        fr256_tile<0>(buf + p * 32768, ld + (p ^ 1) * 32768,
                      gA, gB, lda, ldb, (long)(t + 1) * 64,
                      rb0, rb1, abase, bbase, acc);
    }
    {
        const int p = t & 1;
        fr256_tile<1>(buf + p * 32768, ld,
                      gA, gB, lda, ldb, 0,
                      rb0, rb1, abase, bbase, acc);
    }
}

// ---------------------------------------------------------------------------
// prep: fp32->bf16 for x & W_v, zero lsum, transpose+cast Wq/Wk -> WqT/WkT
// ---------------------------------------------------------------------------
__global__ void prep_kernel(const float* __restrict__ x,
                            const float* __restrict__ wq,
                            const float* __restrict__ wk,
                            const float* __restrict__ wv,
                            ushort_t* __restrict__ xb,
                            ushort_t* __restrict__ wvb,
                            ushort_t* __restrict__ wqT,
                            ushort_t* __restrict__ wkT,
                            float* __restrict__ lsum) {
    const int bx = blockIdx.x;
    const int t = threadIdx.x;
    if (bx < 9216) {
        const float* src;
        ushort_t* dst;
        long g;
        if (bx < 8192) { src = x;  dst = xb;  g = ((long)bx * 256 + t) * 4; }
        else           { src = wv; dst = wvb; g = ((long)(bx - 8192) * 256 + t) * 4; }
        float4 v = *(const float4*)(src + g);
        ushort4 o;
        o.x = f2bf(v.x); o.y = f2bf(v.y); o.z = f2bf(v.z); o.w = f2bf(v.w);
        *(ushort4*)(dst + g) = o;
        return;
    }
    if (bx < 9224) {
        int idx = (bx - 9216) * 256 + t;  // [0,2048)
        ((float4*)lsum)[idx] = (float4){0.f, 0.f, 0.f, 0.f};
        return;
    }
    const int tt = bx - 9224;           // [0,512)
    const float* src = (tt >= 256) ? wk : wq;
    ushort_t* dst = (tt >= 256) ? wkT : wqT;
    const int id = tt & 255;
    const int h0 = (id >> 4) * 64, d0 = (id & 15) * 64;
    __shared__ ushort_t tile[64 * 80];
    {
        int i = t >> 2, cg = (t & 3) << 4;
        const float4* p = (const float4*)(src + (long)(h0 + i) * 1024 + d0 + cg);
#pragma unroll
        for (int k = 0; k < 4; k++) {
            float4 v = p[k];
            ushort_t* q = &tile[i * 80 + cg + k * 4];
            q[0] = f2bf(v.x); q[1] = f2bf(v.y); q[2] = f2bf(v.z); q[3] = f2bf(v.w);
        }
    }
    __syncthreads();
    {
        int j = t >> 2, ig = (t & 3) << 4;
        ushort_t tmp[16];
#pragma unroll
        for (int k = 0; k < 16; k++) tmp[k] = tile[(ig + k) * 80 + j];
        ushort_t* o = dst + (long)(d0 + j) * 1024 + h0 + ig;
        *(uint4*)o = ((uint4*)tmp)[0];
        *(uint4*)(o + 8) = ((uint4*)tmp)[1];
    }
}

// ---------------------------------------------------------------------------
// gv: blocks [0,32) -> G (8m x 4n of 128x256) ; [32,288) -> V^T (8m x 32n).
// free-run t3 core, 288 blocks (swizzle cpx=36, bijective).
// ---------------------------------------------------------------------------
__global__ __launch_bounds__(512, 2) void gv_kernel(
    const ushort_t* __restrict__ wkT, const ushort_t* __restrict__ wqT,
    const ushort_t* __restrict__ wvb, const ushort_t* __restrict__ xb,
    ushort_t* __restrict__ Gb, ushort_t* __restrict__ VTb) {

    __shared__ __align__(16) ushort_t buf[73728];   // 144 KB

    const int lin = xcd_swz(blockIdx.x, 36);
    const ushort_t *A, *B;
    ushort_t* C;
    int ldc, tile_m, tile_n;
    if (lin < 32) {          // G[e][d] = sum_h WkT[e][h] WqT[d][h]
        A = wkT; B = wqT; C = Gb; ldc = 1024;
        tile_m = (lin >> 2) * 128;          // 8 m-tiles
        tile_n = (lin & 3) * 256;           // 4 n-tiles
    } else {                 // VT[h][s] = sum_d Wv[h][d] x[s][d]
        int id = lin - 32;                  // [0,256)
        A = wvb; B = xb; C = VTb; ldc = 8192;
        tile_m = (id >> 5) * 128;           // 8 m-tiles
        tile_n = (id & 31) * 256;           // 32 n-tiles
    }

    floatx4 acc[4][4];
    gemm_frbn(A, 1024, B, 1024, 1024, tile_m, tile_n, buf, acc);

    const int lane = threadIdx.x & 63, wave = threadIdx.x >> 6;
    const int wm = wave >> 2, wn = wave & 3, quad = lane >> 4, l16 = lane & 15;
#pragma unroll
    for (int fr = 0; fr < 4; fr++)
#pragma unroll
        for (int r = 0; r < 4; r++) {
            int row = tile_m + wm * 64 + fr * 16 + quad * 4 + r;
#pragma unroll
            for (int fc = 0; fc < 4; fc++) {
                int col = tile_n + fc * 64 + wn * 16 + l16;
                C[(long)row * ldc + col] = f2bf(acc[fr][fc][r]);
            }
        }
}

// ---------------------------------------------------------------------------
// Y = x G^T  (M=8192, N=1024, K=1024; 128x256 tiles, 256 blocks = 1/CU)
// ---------------------------------------------------------------------------
__global__ __launch_bounds__(512, 2) void y_kernel(
    const ushort_t* __restrict__ xb,
    const ushort_t* __restrict__ Gb,
    ushort_t* __restrict__ Yb) {

    __shared__ __align__(16) ushort_t buf[73728];   // 144 KB
    const int lin = xcd_swz(blockIdx.x, 32);        // 256 blocks
    const int tile_m = (lin >> 2) * 128;            // 64 m-tiles
    const int tile_n = (lin & 3) * 256;             // 4 n-tiles (fastest)

    floatx4 acc[4][4];
    gemm_frbn(xb, 1024, Gb, 1024, 1024, tile_m, tile_n, buf, acc);

    const int lane = threadIdx.x & 63, wave = threadIdx.x >> 6;
    const int wm = wave >> 2, wn = wave & 3, quad = lane >> 4, l16 = lane & 15;
#pragma unroll
    for (int fr = 0; fr < 4; fr++)
#pragma unroll
        for (int r = 0; r < 4; r++) {
            int row = tile_m + wm * 64 + fr * 16 + quad * 4 + r;
#pragma unroll
            for (int fc = 0; fc < 4; fc++) {
                int col = tile_n + fc * 64 + wn * 16 + l16;
                Yb[(long)row * 1024 + col] = f2bf(acc[fr][fc][r]);
            }
        }
}

// ---------------------------------------------------------------------------
// P = exp(scale * Y x^T) per batch + fused row-sum atomics.
// free-run d2 256x256 core, 256 blocks = 1/CU, 128 KB LDS.
// ---------------------------------------------------------------------------
__global__ __launch_bounds__(512, 2) void pexp_kernel(
    const ushort_t* __restrict__ Yb,
    const ushort_t* __restrict__ xb,
    ushort_t* __restrict__ Pb,
    float* __restrict__ lsum) {

    __shared__ __align__(16) ushort_t buf[65536];   // 128 KB

    const int lin = xcd_swz(blockIdx.x, 32);   // 256 blocks, bijective
    const int z = lin >> 6;                    // batch
    const int tile_m = ((lin >> 3) & 7) * 256; // 8 m-tiles
    const int tile_n = (lin & 7) * 256;        // 8 n-tiles

    const ushort_t* A = Yb + (long)z * 2097152;
    const ushort_t* B = xb + (long)z * 2097152;
    ushort_t* C = Pb + (long)z * 4194304;
    float* l = lsum + z * 2048;

    floatx4 acc[8][4];
    gemm_fr256(A, 1024, B, 1024, 1024, tile_m, tile_n, buf, acc);

    const float scale = 0.022097086912079608f;  // 1/sqrt(2048)
    const int lane = threadIdx.x & 63, wave = threadIdx.x >> 6;
    const int wm = wave >> 2, wn = wave & 3, quad = lane >> 4, l16 = lane & 15;
#pragma unroll
    for (int fr = 0; fr < 8; fr++)
#pragma unroll
        for (int rr = 0; rr < 4; rr++) {
            int row = tile_m + wm * 128 + fr * 16 + quad * 4 + rr;
            float psum = 0.f;
#pragma unroll
            for (int fc = 0; fc < 4; fc++) {
                int col = tile_n + wn * 64 + fc * 16 + l16;
                float e = __expf(acc[fr][fc][rr] * scale);
                C[(long)row * 2048 + col] = f2bf(e);
                psum += e;
            }
            psum += __shfl_xor(psum, 1, 64);
            psum += __shfl_xor(psum, 2, 64);
            psum += __shfl_xor(psum, 4, 64);
            psum += __shfl_xor(psum, 8, 64);
            if (l16 == 0) atomicAdd(&l[row], psum);
        }
}

// ---------------------------------------------------------------------------
// out = (P V) / l per batch  (128x256 tiles, K=2048, 256 blocks = 1/CU)
// ---------------------------------------------------------------------------
__global__ __launch_bounds__(512, 2) void out_kernel(
    const ushort_t* __restrict__ Pb,
    const ushort_t* __restrict__ VTb,
    float* __restrict__ out,
    const float* __restrict__ lsum) {

    __shared__ __align__(16) ushort_t buf[73728];   // 144 KB

    const int lin = xcd_swz(blockIdx.x, 32);   // 256 blocks
    const int z = lin >> 6;                    // batch
    const int tile_m = ((lin >> 2) & 15) * 128;// 16 m-tiles
    const int tile_n = (lin & 3) * 256;        // 4 n-tiles (fastest)

    const ushort_t* A = Pb + (long)z * 4194304;   // [2048][2048]
    const ushort_t* B = VTb + (long)z * 2048;     // ldb=8192, batch col slice
    float* C = out + (long)z * 2097152;
    const float* l = lsum + z * 2048;

    floatx4 acc[4][4];
    gemm_frbn(A, 2048, B, 8192, 2048, tile_m, tile_n, buf, acc);

    const int lane = threadIdx.x & 63, wave = threadIdx.x >> 6;
    const int wm = wave >> 2, wn = wave & 3, quad = lane >> 4, l16 = lane & 15;
#pragma unroll
    for (int fr = 0; fr < 4; fr++)
#pragma unroll
        for (int r = 0; r < 4; r++) {
            int row = tile_m + wm * 64 + fr * 16 + quad * 4 + r;
            float li = 1.0f / l[row];
#pragma unroll
            for (int fc = 0; fc < 4; fc++) {
                int col = tile_n + fc * 64 + wn * 16 + l16;
                C[(long)row * 1024 + col] = acc[fr][fc][r] * li;
            }
        }
}

// ---------------------------------------------------------------------------
extern "C" void kernel_launch(void* const* d_in, const int* in_sizes, int n_in,
                              void* d_out, int out_size, void* d_ws, size_t ws_size,
                              hipStream_t stream) {
    const float* x  = (const float*)d_in[0];
    const float* wq = (const float*)d_in[1];
    const float* wk = (const float*)d_in[2];
    const float* wv = (const float*)d_in[3];

    ushort_t* xb  = (ushort_t*)d_ws;          // [8192,1024] bf16
    ushort_t* wvb = xb  + 8388608;            // [1024,1024]
    ushort_t* wqT = wvb + 1048576;            // [1024,1024]
    ushort_t* wkT = wqT + 1048576;            // [1024,1024]
    ushort_t* Gb  = wkT + 1048576;            // [1024,1024]
    ushort_t* Yb  = Gb  + 1048576;            // [8192,1024]
    ushort_t* VTb = Yb  + 8388608;            // [1024,8192]
    ushort_t* Pb  = VTb + 8388608;            // [4][2048][2048]
    float*    lsum = (float*)(Pb + 16777216); // [4][2048]
    float*    out  = (float*)d_out;

    prep_kernel<<<9736, 256, 0, stream>>>(x, wq, wk, wv, xb, wvb, wqT, wkT, lsum);
    gv_kernel<<<288, 512, 0, stream>>>(wkT, wqT, wvb, xb, Gb, VTb);
    y_kernel<<<256, 512, 0, stream>>>(xb, Gb, Yb);
    pexp_kernel<<<256, 512, 0, stream>>>(Yb, xb, Pb, lsum);
    out_kernel<<<256, 512, 0, stream>>>(Pb, VTb, out, lsum);
}